// Round 3
// baseline (181.122 us; speedup 1.0000x reference)
//
#include <hip/hip_runtime.h>

// Sizes: B=32, T=336, D=512, H=8, HD=64; M = B*T = 10752.
// hour classes: 24 classes x 14 members; day classes: 7 classes x 48 members.

typedef __attribute__((ext_vector_type(8))) __bf16 bf16x8;
typedef __attribute__((ext_vector_type(4))) float f32x4;

__device__ __forceinline__ unsigned short f2bf(float f) {
  union { float f; unsigned u; } v; v.f = f;
  unsigned r = v.u + 0x7fffu + ((v.u >> 16) & 1u);
  return (unsigned short)(r >> 16);
}
__device__ __forceinline__ float bf2f(unsigned short u) {
  union { unsigned u; float f; } v; v.u = ((unsigned)u) << 16;
  return v.f;
}

__device__ __forceinline__ void load_lds16(const void* g, void* l) {
  __builtin_amdgcn_global_load_lds(
      (const __attribute__((address_space(1))) void*)g,
      (__attribute__((address_space(3))) void*)l, 16, 0, 0);
}

// ---------------------------------------------------------------------------
// C = A [M][K] * Bt^T, Bt stored [N][K] (both bf16 row-major, k-contiguous).
// 128x128 tile, BK=32, 4 waves (2x2 of 64x64), mfma_f32_16x16x32_bf16.
// OUT_BF16: write bf16 (no bias); else f32 with optional bias.
// ---------------------------------------------------------------------------
template <bool OUT_BF16>
__global__ __launch_bounds__(256) void gemm_bt(
    const unsigned short* __restrict__ A, const unsigned short* __restrict__ Bt,
    void* __restrict__ Cv, const float* __restrict__ bias, int M, int N, int K) {
  __shared__ __align__(16) unsigned short As[128 * 32];
  __shared__ __align__(16) unsigned short Bs[128 * 32];
  const int tid = threadIdx.x;
  const int lane = tid & 63;
  const int wid = tid >> 6;
  const int ntile = N >> 7;
  const int bx = blockIdx.x % ntile;
  const int by = blockIdx.x / ntile;
  const long row0 = (long)by << 7;
  const long col0 = (long)bx << 7;
  const int wr = (wid >> 1) << 6;
  const int wc = (wid & 1) << 6;

  const unsigned short* ag[2];
  const unsigned short* bg[2];
  int lofs[2];
#pragma unroll
  for (int it = 0; it < 2; ++it) {
    const int s = tid + (it << 8);
    const int r = s >> 2;
    const int ks = (s & 3) << 3;
    ag[it] = A + (row0 + r) * (long)K + ks;
    bg[it] = Bt + (col0 + r) * (long)K + ks;
    lofs[it] = s << 4;  // byte offset in LDS
  }

  f32x4 acc[4][4];
  const f32x4 zero = {0.f, 0.f, 0.f, 0.f};
#pragma unroll
  for (int m = 0; m < 4; ++m)
#pragma unroll
    for (int n = 0; n < 4; ++n) acc[m][n] = zero;

  const int fr = lane & 15;
  const int krow = (lane >> 4) << 3;

  for (int kk = 0; kk < K; kk += 32) {
#pragma unroll
    for (int it = 0; it < 2; ++it) {
      load_lds16(ag[it] + kk, (char*)As + lofs[it]);
      load_lds16(bg[it] + kk, (char*)Bs + lofs[it]);
    }
    __syncthreads();
    bf16x8 a[4], b[4];
#pragma unroll
    for (int m = 0; m < 4; ++m)
      a[m] = *(const bf16x8*)(const void*)(As + (wr + m * 16 + fr) * 32 + krow);
#pragma unroll
    for (int n = 0; n < 4; ++n)
      b[n] = *(const bf16x8*)(const void*)(Bs + (wc + n * 16 + fr) * 32 + krow);
#pragma unroll
    for (int m = 0; m < 4; ++m)
#pragma unroll
      for (int n = 0; n < 4; ++n)
        acc[m][n] = __builtin_amdgcn_mfma_f32_16x16x32_bf16(a[m], b[n], acc[m][n], 0, 0, 0);
    __syncthreads();
  }

  // C/D layout: col = lane&15, row = (lane>>4)*4 + reg  [measured m89/m91]
  const int orow = (lane >> 4) << 2;
  const int ocol = lane & 15;
#pragma unroll
  for (int m = 0; m < 4; ++m) {
#pragma unroll
    for (int n = 0; n < 4; ++n) {
      const long gcol = col0 + wc + n * 16 + ocol;
      float bv = 0.f;
      if (!OUT_BF16 && bias) bv = bias[gcol];
#pragma unroll
      for (int r = 0; r < 4; ++r) {
        const long grow = row0 + wr + m * 16 + orow + r;
        const float val = acc[m][n][r] + bv;
        if (OUT_BF16)
          ((unsigned short*)Cv)[grow * N + gcol] = f2bf(val);
        else
          ((float*)Cv)[grow * N + gcol] = val;
      }
    }
  }
}

// ---------------------------------------------------------------------------
// Hour attention: block = (b, h, hour class c). 14 queries x 14 keys, HD=64.
// QKV: bf16 [B*T][1536] (q | k | v per head-concat). comb: bf16 [B*T][1024].
// ---------------------------------------------------------------------------
__global__ __launch_bounds__(256) void attn_hour(
    const unsigned short* __restrict__ QKV, const float* __restrict__ bias,
    unsigned short* __restrict__ comb) {
  const int c = blockIdx.x % 24;
  const int h = (blockIdx.x / 24) & 7;
  const int b = blockIdx.x / (24 * 8);
  __shared__ float Qs[14 * 65], Ks[14 * 65], Vs[14 * 65], S[14 * 15];
  const int tid = threadIdx.x;
  const long rowBase = (long)b * 336;

  for (int idx = tid; idx < 14 * 64; idx += 256) {
    const int i = idx >> 6, d = idx & 63;
    const long off = (rowBase + c + 24 * i) * 1536 + h * 64 + d;
    Qs[i * 65 + d] = bf2f(QKV[off]);
    Ks[i * 65 + d] = bf2f(QKV[off + 512]);
    Vs[i * 65 + d] = bf2f(QKV[off + 1024]);
  }
  __syncthreads();
  if (tid < 196) {
    const int i = tid / 14, j = tid - i * 14;
    float dot = 0.f;
#pragma unroll
    for (int d = 0; d < 64; ++d) dot += Qs[i * 65 + d] * Ks[j * 65 + d];
    S[i * 15 + j] = dot * 0.125f + bias[(long)(c + 24 * i) * 336 + (c + 24 * j)];
  }
  __syncthreads();
  if (tid < 14) {
    float mx = -1e30f;
#pragma unroll
    for (int j = 0; j < 14; ++j) mx = fmaxf(mx, S[tid * 15 + j]);
    float sum = 0.f;
#pragma unroll
    for (int j = 0; j < 14; ++j) sum += __expf(S[tid * 15 + j] - mx);
    const float inv = 1.f / sum;
#pragma unroll
    for (int j = 0; j < 14; ++j) S[tid * 15 + j] = __expf(S[tid * 15 + j] - mx) * inv;
  }
  __syncthreads();
  for (int idx = tid; idx < 14 * 64; idx += 256) {
    const int i = idx >> 6, d = idx & 63;
    float o = 0.f;
#pragma unroll
    for (int j = 0; j < 14; ++j) o += S[i * 15 + j] * Vs[j * 65 + d];
    comb[(rowBase + c + 24 * i) * 1024 + h * 64 + d] = f2bf(o);
  }
}

// ---------------------------------------------------------------------------
// Day attention: block = (b, h, day class dc). 48 queries x 48 keys (days dc
// and dc+7), HD=64. Writes cols [512, 1024) of comb.
// ---------------------------------------------------------------------------
__global__ __launch_bounds__(256) void attn_day(
    const unsigned short* __restrict__ QKV, const float* __restrict__ bias,
    unsigned short* __restrict__ comb) {
  const int dc = blockIdx.x % 7;
  const int h = (blockIdx.x / 7) & 7;
  const int b = blockIdx.x / 56;
  __shared__ float Qs[48 * 65], Ks[48 * 65], Vs[48 * 65], S[48 * 49];
  const int tid = threadIdx.x;
  const long rowBase = (long)b * 336;

  for (int idx = tid; idx < 48 * 64; idx += 256) {
    const int i = idx >> 6, d = idx & 63;
    const int t = 24 * dc + i + ((i < 24) ? 0 : 144);
    const long off = (rowBase + t) * 1536 + h * 64 + d;
    Qs[i * 65 + d] = bf2f(QKV[off]);
    Ks[i * 65 + d] = bf2f(QKV[off + 512]);
    Vs[i * 65 + d] = bf2f(QKV[off + 1024]);
  }
  __syncthreads();
  for (int p = tid; p < 48 * 48; p += 256) {
    const int i = p / 48, j = p - i * 48;
    float dot = 0.f;
#pragma unroll
    for (int d = 0; d < 64; ++d) dot += Qs[i * 65 + d] * Ks[j * 65 + d];
    const int tq = 24 * dc + i + ((i < 24) ? 0 : 144);
    const int tk = 24 * dc + j + ((j < 24) ? 0 : 144);
    S[i * 49 + j] = dot * 0.125f + bias[(long)tq * 336 + tk];
  }
  __syncthreads();
  if (tid < 48) {
    float mx = -1e30f;
#pragma unroll
    for (int j = 0; j < 48; ++j) mx = fmaxf(mx, S[tid * 49 + j]);
    float sum = 0.f;
#pragma unroll
    for (int j = 0; j < 48; ++j) sum += __expf(S[tid * 49 + j] - mx);
    const float inv = 1.f / sum;
#pragma unroll
    for (int j = 0; j < 48; ++j) S[tid * 49 + j] = __expf(S[tid * 49 + j] - mx) * inv;
  }
  __syncthreads();
  for (int idx = tid; idx < 48 * 64; idx += 256) {
    const int i = idx >> 6, d = idx & 63;
    float o = 0.f;
#pragma unroll
    for (int j = 0; j < 48; ++j) o += S[i * 49 + j] * Vs[j * 65 + d];
    const int t = 24 * dc + i + ((i < 24) ? 0 : 144);
    comb[(rowBase + t) * 1024 + 512 + h * 64 + d] = f2bf(o);
  }
}

// ---------------------------------------------------------------------------
// Casts
// ---------------------------------------------------------------------------
__global__ void cast_x_k(const float* __restrict__ x, unsigned short* __restrict__ xb, int n4) {
  const int i = blockIdx.x * 256 + threadIdx.x;
  if (i >= n4) return;
  const float4 v = ((const float4*)x)[i];
  ushort4 o;
  o.x = f2bf(v.x); o.y = f2bf(v.y); o.z = f2bf(v.z); o.w = f2bf(v.w);
  ((ushort4*)xb)[i] = o;
}

// WqkvT [1536][512]: n<512 -> Wq col n; 512..1023 -> Wk; else Wv (transposed).
__global__ void cast_wqkvT_k(const float* __restrict__ Wq, const float* __restrict__ Wk,
                             const float* __restrict__ Wv, unsigned short* __restrict__ Wt) {
  const int idx = blockIdx.x * 256 + threadIdx.x;
  if (idx >= 1536 * 512) return;
  const int n = idx >> 9, k = idx & 511;
  const float* W = (n < 512) ? Wq : ((n < 1024) ? Wk : Wv);
  Wt[idx] = f2bf(W[k * 512 + (n & 511)]);
}

// WoT [512][1024] = transpose of Wo [1024][512]
__global__ void cast_woT_k(const float* __restrict__ Wo, unsigned short* __restrict__ Wt) {
  const int idx = blockIdx.x * 256 + threadIdx.x;
  if (idx >= 512 * 1024) return;
  const int n = idx >> 10, k = idx & 1023;
  Wt[idx] = f2bf(Wo[k * 512 + n]);
}

// ---------------------------------------------------------------------------
extern "C" void kernel_launch(void* const* d_in, const int* in_sizes, int n_in,
                              void* d_out, int out_size, void* d_ws, size_t ws_size,
                              hipStream_t stream) {
  (void)in_sizes; (void)n_in; (void)out_size; (void)ws_size;
  const float* x  = (const float*)d_in[0];
  const float* Wq = (const float*)d_in[1];
  const float* Wk = (const float*)d_in[2];
  const float* Wv = (const float*)d_in[3];
  const float* Wo = (const float*)d_in[4];
  const float* bo = (const float*)d_in[5];
  const float* rb = (const float*)d_in[6];

  char* ws = (char*)d_ws;
  unsigned short* xbf   = (unsigned short*)(ws + 0);         // 10752*512*2  = 11,010,048
  unsigned short* WqkvT = (unsigned short*)(ws + 11010048);  // 1536*512*2   =  1,572,864
  unsigned short* WoT   = (unsigned short*)(ws + 12582912);  // 512*1024*2   =  1,048,576
  unsigned short* QKVb  = (unsigned short*)(ws + 13631488);  // 10752*1536*2 = 33,030,144
  unsigned short* comb  = (unsigned short*)(ws + 46661632);  // 10752*1024*2 = 22,020,096
  // total 68,681,728 bytes

  cast_x_k<<<5376, 256, 0, stream>>>(x, xbf, 1376256);
  cast_wqkvT_k<<<3072, 256, 0, stream>>>(Wq, Wk, Wv, WqkvT);
  cast_woT_k<<<2048, 256, 0, stream>>>(Wo, WoT);

  // QKV = x @ [Wq|Wk|Wv]  -> bf16 [10752][1536]
  gemm_bt<true><<<84 * 12, 256, 0, stream>>>(xbf, WqkvT, QKVb, nullptr, 10752, 1536, 512);

  attn_hour<<<32 * 8 * 24, 256, 0, stream>>>(QKVb, rb, comb);
  attn_day<<<32 * 8 * 7, 256, 0, stream>>>(QKVb, rb + 336 * 336, comb);

  // out = comb @ Wo + bo -> f32 [10752][512]
  gemm_bt<false><<<84 * 4, 256, 0, stream>>>(comb, WoT, d_out, bo, 10752, 512, 1024);
}

// Round 6
// 108.375 us; speedup vs baseline: 1.6713x; 1.6713x over previous
//
#include <hip/hip_runtime.h>

// Sizes: B=32, T=336, D=512, H=8, HD=64; M = B*T = 10752.
// hour classes: 24 classes x 14 members; day classes: 7 classes x 48 members
// (days dc and dc+7).

typedef __attribute__((ext_vector_type(8))) __bf16 bf16x8;
typedef __attribute__((ext_vector_type(8))) unsigned short u16x8;
typedef __attribute__((ext_vector_type(4))) float f32x4;

__device__ __forceinline__ unsigned short f2bf(float f) {
  union { float f; unsigned u; } v; v.f = f;
  unsigned r = v.u + 0x7fffu + ((v.u >> 16) & 1u);
  return (unsigned short)(r >> 16);
}

__device__ __forceinline__ void load_lds16(const void* g, void* l) {
  __builtin_amdgcn_global_load_lds(
      (const __attribute__((address_space(1))) void*)g,
      (__attribute__((address_space(3))) void*)l, 16, 0, 0);
}

// ---------------------------------------------------------------------------
// C = A [M][K] * Bt^T, Bt stored [N][K] (both bf16 row-major, k-contiguous).
// 128x128 tile, BK=32, 4 waves (2x2 of 64x64), mfma_f32_16x16x32_bf16.
// ---------------------------------------------------------------------------
template <bool OUT_BF16>
__global__ __launch_bounds__(256) void gemm_bt(
    const unsigned short* __restrict__ A, const unsigned short* __restrict__ Bt,
    void* __restrict__ Cv, const float* __restrict__ bias, int M, int N, int K) {
  __shared__ __align__(16) unsigned short As[128 * 32];
  __shared__ __align__(16) unsigned short Bs[128 * 32];
  const int tid = threadIdx.x;
  const int lane = tid & 63;
  const int wid = tid >> 6;
  const int ntile = N >> 7;
  const int bx = blockIdx.x % ntile;
  const int by = blockIdx.x / ntile;
  const long row0 = (long)by << 7;
  const long col0 = (long)bx << 7;
  const int wr = (wid >> 1) << 6;
  const int wc = (wid & 1) << 6;

  const unsigned short* ag[2];
  const unsigned short* bg[2];
  int lofs[2];
#pragma unroll
  for (int it = 0; it < 2; ++it) {
    const int s = tid + (it << 8);
    const int r = s >> 2;
    const int ks = (s & 3) << 3;
    ag[it] = A + (row0 + r) * (long)K + ks;
    bg[it] = Bt + (col0 + r) * (long)K + ks;
    lofs[it] = s << 4;  // byte offset in LDS
  }

  f32x4 acc[4][4];
  const f32x4 zero = {0.f, 0.f, 0.f, 0.f};
#pragma unroll
  for (int m = 0; m < 4; ++m)
#pragma unroll
    for (int n = 0; n < 4; ++n) acc[m][n] = zero;

  const int fr = lane & 15;
  const int krow = (lane >> 4) << 3;

  for (int kk = 0; kk < K; kk += 32) {
#pragma unroll
    for (int it = 0; it < 2; ++it) {
      load_lds16(ag[it] + kk, (char*)As + lofs[it]);
      load_lds16(bg[it] + kk, (char*)Bs + lofs[it]);
    }
    __syncthreads();
    bf16x8 a[4], b[4];
#pragma unroll
    for (int m = 0; m < 4; ++m)
      a[m] = *(const bf16x8*)(const void*)(As + (wr + m * 16 + fr) * 32 + krow);
#pragma unroll
    for (int n = 0; n < 4; ++n)
      b[n] = *(const bf16x8*)(const void*)(Bs + (wc + n * 16 + fr) * 32 + krow);
#pragma unroll
    for (int m = 0; m < 4; ++m)
#pragma unroll
      for (int n = 0; n < 4; ++n)
        acc[m][n] = __builtin_amdgcn_mfma_f32_16x16x32_bf16(a[m], b[n], acc[m][n], 0, 0, 0);
    __syncthreads();
  }

  // C/D layout: col = lane&15, row = (lane>>4)*4 + reg  [measured m89/m91]
  const int orow = (lane >> 4) << 2;
  const int ocol = lane & 15;
#pragma unroll
  for (int m = 0; m < 4; ++m) {
#pragma unroll
    for (int n = 0; n < 4; ++n) {
      const long gcol = col0 + wc + n * 16 + ocol;
      float bv = 0.f;
      if (!OUT_BF16 && bias) bv = bias[gcol];
#pragma unroll
      for (int r = 0; r < 4; ++r) {
        const long grow = row0 + wr + m * 16 + orow + r;
        const float val = acc[m][n][r] + bv;
        if (OUT_BF16)
          ((unsigned short*)Cv)[grow * N + gcol] = f2bf(val);
        else
          ((float*)Cv)[grow * N + gcol] = val;
      }
    }
  }
}

// ---------------------------------------------------------------------------
// MFMA attention, one wave per (b, h, class).
// MODE 0 = hour (14 members, t = c + 24*i), writes comb cols [0,512).
// MODE 1 = day (48 members, days dc & dc+7),   writes comb cols [512,1024).
// QK^T via mfma_16x16x32_bf16 with Q,K fragments loaded straight from global;
// softmax in-register (shfl_xor over the 16-lane col group);
// P -> LDS bf16 (padded rows), V staged transposed; PV via MFMA.
// ---------------------------------------------------------------------------
template <int MODE>
__global__ __launch_bounds__(64) void attn_mfma(
    const unsigned short* __restrict__ QKV, const float* __restrict__ bias,
    unsigned short* __restrict__ comb) {
  constexpr int NQT = MODE ? 3 : 1;   // 16-row query tiles
  constexpr int NKT = MODE ? 3 : 1;   // 16-col key tiles
  constexpr int PVK = MODE ? 2 : 1;   // PV k-steps of 32 keys
  constexpr int MEM = MODE ? 48 : 14; // members per class
  constexpr int PLD = MODE ? 72 : 40; // P_lds row stride (elems, 16B-aligned, bank-rotated)
  constexpr int VLD = MODE ? 72 : 40; // Vt row stride
  constexpr int NCLS = MODE ? 7 : 24;

  const int cls = blockIdx.x % NCLS;
  const int h = (blockIdx.x / NCLS) & 7;
  const int b = blockIdx.x / (NCLS * 8);
  const int lane = threadIdx.x & 63;
  const long rowBase = (long)b * 336;

  __shared__ __align__(16) unsigned short P_lds[16 * NQT * PLD];
  __shared__ __align__(16) unsigned short Vt[64 * VLD];

  // t-mapping: class member i -> timestep
  auto tmap = [&](int i) -> int {
    if (MODE) return 24 * cls + i + ((i < 24) ? 0 : 144);
    return cls + 24 * i;
  };

  // ---- zero LDS (pad keys must multiply P as exact 0) ----
  {
    const uint4 z4 = {0u, 0u, 0u, 0u};
    uint4* p4 = (uint4*)P_lds;
#pragma unroll
    for (int i = 0; i < (int)(sizeof(P_lds) / 16 / 64) + 1; ++i) {
      const int idx = lane + i * 64;
      if (idx < (int)(sizeof(P_lds) / 16)) p4[idx] = z4;
    }
    uint4* v4 = (uint4*)Vt;
#pragma unroll
    for (int i = 0; i < (int)(sizeof(Vt) / 16 / 64) + 1; ++i) {
      const int idx = lane + i * 64;
      if (idx < (int)(sizeof(Vt) / 16)) v4[idx] = z4;
    }
  }
  __syncthreads();

  // ---- stage V transposed: Vt[d][k] (bf16), keys >= MEM stay zero ----
  {
    const int kloc = lane >> 3;        // 0..7 within pass
    const int d0 = (lane & 7) * 8;     // d octet
    constexpr int NPASS = (MEM + 7) / 8;
#pragma unroll
    for (int p = 0; p < NPASS; ++p) {
      const int k = p * 8 + kloc;
      if (k < MEM) {
        const long off = (rowBase + tmap(k)) * 1536 + 1024 + h * 64 + d0;
        const u16x8 vv = *(const u16x8*)(const void*)(QKV + off);
#pragma unroll
        for (int e = 0; e < 8; ++e) Vt[(d0 + e) * VLD + k] = vv[e];
      }
    }
  }

  // ---- Q,K fragments straight from global ----
  const int fr = lane & 15;
  const int kgrp = (lane >> 4) << 3;  // k-octet within 32-wide step
  bf16x8 aq[NQT][2], bk[NKT][2];
#pragma unroll
  for (int it = 0; it < NQT; ++it) {
    const int qi = 16 * it + fr;
    const long rq = (rowBase + tmap(qi < MEM ? qi : MEM - 1)) * 1536 + h * 64 + kgrp;
#pragma unroll
    for (int ks = 0; ks < 2; ++ks)
      aq[it][ks] = *(const bf16x8*)(const void*)(QKV + rq + ks * 32);
  }
#pragma unroll
  for (int jt = 0; jt < NKT; ++jt) {
    const int kj = 16 * jt + fr;
    const long rk = (rowBase + tmap(kj < MEM ? kj : MEM - 1)) * 1536 + 512 + h * 64 + kgrp;
#pragma unroll
    for (int ks = 0; ks < 2; ++ks)
      bk[jt][ks] = *(const bf16x8*)(const void*)(QKV + rk + ks * 32);
  }

  // ---- QK^T ----
  f32x4 sacc[NQT][NKT];
  const f32x4 zero = {0.f, 0.f, 0.f, 0.f};
#pragma unroll
  for (int it = 0; it < NQT; ++it)
#pragma unroll
    for (int jt = 0; jt < NKT; ++jt) sacc[it][jt] = zero;
#pragma unroll
  for (int ks = 0; ks < 2; ++ks)
#pragma unroll
    for (int it = 0; it < NQT; ++it)
#pragma unroll
      for (int jt = 0; jt < NKT; ++jt)
        sacc[it][jt] = __builtin_amdgcn_mfma_f32_16x16x32_bf16(aq[it][ks], bk[jt][ks], sacc[it][jt], 0, 0, 0);

  // ---- bias + mask + softmax (in-register, rows in 16-lane groups) ----
  const int rgrp = (lane >> 4) << 2;  // C-layout row group base
#pragma unroll
  for (int it = 0; it < NQT; ++it) {
#pragma unroll
    for (int r = 0; r < 4; ++r) {
      const int row = 16 * it + rgrp + r;
      const int tq = tmap(row < MEM ? row : MEM - 1);
      float sv[NKT];
#pragma unroll
      for (int jt = 0; jt < NKT; ++jt) {
        const int col = 16 * jt + fr;
        const int tk = tmap(col < MEM ? col : MEM - 1);
        sv[jt] = sacc[it][jt][r] * 0.125f + bias[(long)tq * 336 + tk];
        if (MODE == 0 && col >= MEM) sv[jt] = -1e30f;
      }
      float m = sv[0];
#pragma unroll
      for (int jt = 1; jt < NKT; ++jt) m = fmaxf(m, sv[jt]);
#pragma unroll
      for (int d = 1; d < 16; d <<= 1) m = fmaxf(m, __shfl_xor(m, d, 64));
      float e[NKT], sum = 0.f;
#pragma unroll
      for (int jt = 0; jt < NKT; ++jt) { e[jt] = __expf(sv[jt] - m); sum += e[jt]; }
#pragma unroll
      for (int d = 1; d < 16; d <<= 1) sum += __shfl_xor(sum, d, 64);
      const float inv = 1.f / sum;
#pragma unroll
      for (int jt = 0; jt < NKT; ++jt)
        P_lds[row * PLD + 16 * jt + fr] = f2bf(e[jt] * inv);
    }
  }
  __syncthreads();

  // ---- PV: O[MEM x 64] = P @ V ----
  f32x4 oacc[NQT][4];
#pragma unroll
  for (int it = 0; it < NQT; ++it)
#pragma unroll
    for (int jt = 0; jt < 4; ++jt) oacc[it][jt] = zero;
#pragma unroll
  for (int ks = 0; ks < PVK; ++ks) {
    bf16x8 pa[NQT], vb[4];
#pragma unroll
    for (int it = 0; it < NQT; ++it)
      pa[it] = *(const bf16x8*)(const void*)(P_lds + (16 * it + fr) * PLD + ks * 32 + kgrp);
#pragma unroll
    for (int jt = 0; jt < 4; ++jt)
      vb[jt] = *(const bf16x8*)(const void*)(Vt + (16 * jt + fr) * VLD + ks * 32 + kgrp);
#pragma unroll
    for (int it = 0; it < NQT; ++it)
#pragma unroll
      for (int jt = 0; jt < 4; ++jt)
        oacc[it][jt] = __builtin_amdgcn_mfma_f32_16x16x32_bf16(pa[it], vb[jt], oacc[it][jt], 0, 0, 0);
  }

  // ---- store ----
  const long colBase = (MODE ? 512 : 0) + h * 64;
#pragma unroll
  for (int it = 0; it < NQT; ++it) {
#pragma unroll
    for (int r = 0; r < 4; ++r) {
      const int row = 16 * it + rgrp + r;
      if (row < MEM) {
        const long base = (rowBase + tmap(row)) * 1024 + colBase;
#pragma unroll
        for (int jt = 0; jt < 4; ++jt)
          comb[base + 16 * jt + fr] = f2bf(oacc[it][jt][r]);
      }
    }
  }
}

// ---------------------------------------------------------------------------
// Casts
// ---------------------------------------------------------------------------
__global__ void cast_x_k(const float* __restrict__ x, unsigned short* __restrict__ xb, int n4) {
  const int i = blockIdx.x * 256 + threadIdx.x;
  if (i >= n4) return;
  const float4 v = ((const float4*)x)[i];
  ushort4 o;
  o.x = f2bf(v.x); o.y = f2bf(v.y); o.z = f2bf(v.z); o.w = f2bf(v.w);
  ((ushort4*)xb)[i] = o;
}

// WqkvT [1536][512]: n<512 -> Wq col n; 512..1023 -> Wk; else Wv (transposed).
__global__ void cast_wqkvT_k(const float* __restrict__ Wq, const float* __restrict__ Wk,
                             const float* __restrict__ Wv, unsigned short* __restrict__ Wt) {
  const int idx = blockIdx.x * 256 + threadIdx.x;
  if (idx >= 1536 * 512) return;
  const int n = idx >> 9, k = idx & 511;
  const float* W = (n < 512) ? Wq : ((n < 1024) ? Wk : Wv);
  Wt[idx] = f2bf(W[k * 512 + (n & 511)]);
}

// WoT [512][1024] = transpose of Wo [1024][512]
__global__ void cast_woT_k(const float* __restrict__ Wo, unsigned short* __restrict__ Wt) {
  const int idx = blockIdx.x * 256 + threadIdx.x;
  if (idx >= 512 * 1024) return;
  const int n = idx >> 10, k = idx & 1023;
  Wt[idx] = f2bf(Wo[k * 512 + n]);
}

// ---------------------------------------------------------------------------
extern "C" void kernel_launch(void* const* d_in, const int* in_sizes, int n_in,
                              void* d_out, int out_size, void* d_ws, size_t ws_size,
                              hipStream_t stream) {
  (void)in_sizes; (void)n_in; (void)out_size; (void)ws_size;
  const float* x  = (const float*)d_in[0];
  const float* Wq = (const float*)d_in[1];
  const float* Wk = (const float*)d_in[2];
  const float* Wv = (const float*)d_in[3];
  const float* Wo = (const float*)d_in[4];
  const float* bo = (const float*)d_in[5];
  const float* rb = (const float*)d_in[6];

  char* ws = (char*)d_ws;
  unsigned short* xbf   = (unsigned short*)(ws + 0);         // 10752*512*2  = 11,010,048
  unsigned short* WqkvT = (unsigned short*)(ws + 11010048);  // 1536*512*2   =  1,572,864
  unsigned short* WoT   = (unsigned short*)(ws + 12582912);  // 512*1024*2   =  1,048,576
  unsigned short* QKVb  = (unsigned short*)(ws + 13631488);  // 10752*1536*2 = 33,030,144
  unsigned short* comb  = (unsigned short*)(ws + 46661632);  // 10752*1024*2 = 22,020,096
  // total 68,681,728 bytes

  cast_x_k<<<5376, 256, 0, stream>>>(x, xbf, 1376256);
  cast_wqkvT_k<<<3072, 256, 0, stream>>>(Wq, Wk, Wv, WqkvT);
  cast_woT_k<<<2048, 256, 0, stream>>>(Wo, WoT);

  // QKV = x @ [Wq|Wk|Wv]  -> bf16 [10752][1536]
  gemm_bt<true><<<84 * 12, 256, 0, stream>>>(xbf, WqkvT, QKVb, nullptr, 10752, 1536, 512);

  attn_mfma<0><<<32 * 8 * 24, 64, 0, stream>>>(QKVb, rb, comb);
  attn_mfma<1><<<32 * 8 * 7, 64, 0, stream>>>(QKVb, rb + 336 * 336, comb);

  // out = comb @ Wo + bo -> f32 [10752][512]
  gemm_bt<false><<<84 * 4, 256, 0, stream>>>(comb, WoT, d_out, bo, 10752, 512, 1024);
}

// Round 7
// 103.054 us; speedup vs baseline: 1.7575x; 1.0516x over previous
//
#include <hip/hip_runtime.h>

// Sizes: B=32, T=336, D=512, H=8, HD=64; M = B*T = 10752.
// hour classes: 24 classes x 14 members; day classes: 7 classes x 48 members
// (days dc and dc+7).

typedef __attribute__((ext_vector_type(8))) __bf16 bf16x8;
typedef __attribute__((ext_vector_type(8))) unsigned short u16x8;
typedef __attribute__((ext_vector_type(4))) float f32x4;

__device__ __forceinline__ unsigned short f2bf(float f) {
  union { float f; unsigned u; } v; v.f = f;
  unsigned r = v.u + 0x7fffu + ((v.u >> 16) & 1u);
  return (unsigned short)(r >> 16);
}

__device__ __forceinline__ void load_lds16(const void* g, void* l) {
  __builtin_amdgcn_global_load_lds(
      (const __attribute__((address_space(1))) void*)g,
      (__attribute__((address_space(3))) void*)l, 16, 0, 0);
}

// ---------------------------------------------------------------------------
// C = A [M][K] * Bt^T, Bt stored [N][K] (both bf16 row-major, k-contiguous).
// 128x128 tile, BK=32, 4 waves (2x2 of 64x64), mfma_f32_16x16x32_bf16.
// (verified: rounds 3/6, absmax 1.95e-3)
// ---------------------------------------------------------------------------
template <bool OUT_BF16>
__global__ __launch_bounds__(256) void gemm_bt(
    const unsigned short* __restrict__ A, const unsigned short* __restrict__ Bt,
    void* __restrict__ Cv, const float* __restrict__ bias, int M, int N, int K) {
  __shared__ __align__(16) unsigned short As[128 * 32];
  __shared__ __align__(16) unsigned short Bs[128 * 32];
  const int tid = threadIdx.x;
  const int lane = tid & 63;
  const int wid = tid >> 6;
  const int ntile = N >> 7;
  const int bx = blockIdx.x % ntile;
  const int by = blockIdx.x / ntile;
  const long row0 = (long)by << 7;
  const long col0 = (long)bx << 7;
  const int wr = (wid >> 1) << 6;
  const int wc = (wid & 1) << 6;

  const unsigned short* ag[2];
  const unsigned short* bg[2];
  int lofs[2];
#pragma unroll
  for (int it = 0; it < 2; ++it) {
    const int s = tid + (it << 8);
    const int r = s >> 2;
    const int ks = (s & 3) << 3;
    ag[it] = A + (row0 + r) * (long)K + ks;
    bg[it] = Bt + (col0 + r) * (long)K + ks;
    lofs[it] = s << 4;  // byte offset in LDS
  }

  f32x4 acc[4][4];
  const f32x4 zero = {0.f, 0.f, 0.f, 0.f};
#pragma unroll
  for (int m = 0; m < 4; ++m)
#pragma unroll
    for (int n = 0; n < 4; ++n) acc[m][n] = zero;

  const int fr = lane & 15;
  const int krow = (lane >> 4) << 3;

  for (int kk = 0; kk < K; kk += 32) {
#pragma unroll
    for (int it = 0; it < 2; ++it) {
      load_lds16(ag[it] + kk, (char*)As + lofs[it]);
      load_lds16(bg[it] + kk, (char*)Bs + lofs[it]);
    }
    __syncthreads();
    bf16x8 a[4], b[4];
#pragma unroll
    for (int m = 0; m < 4; ++m)
      a[m] = *(const bf16x8*)(const void*)(As + (wr + m * 16 + fr) * 32 + krow);
#pragma unroll
    for (int n = 0; n < 4; ++n)
      b[n] = *(const bf16x8*)(const void*)(Bs + (wc + n * 16 + fr) * 32 + krow);
#pragma unroll
    for (int m = 0; m < 4; ++m)
#pragma unroll
      for (int n = 0; n < 4; ++n)
        acc[m][n] = __builtin_amdgcn_mfma_f32_16x16x32_bf16(a[m], b[n], acc[m][n], 0, 0, 0);
    __syncthreads();
  }

  // C/D layout: col = lane&15, row = (lane>>4)*4 + reg  [measured m89/m91]
  const int orow = (lane >> 4) << 2;
  const int ocol = lane & 15;
#pragma unroll
  for (int m = 0; m < 4; ++m) {
#pragma unroll
    for (int n = 0; n < 4; ++n) {
      const long gcol = col0 + wc + n * 16 + ocol;
      float bv = 0.f;
      if (!OUT_BF16 && bias) bv = bias[gcol];
#pragma unroll
      for (int r = 0; r < 4; ++r) {
        const long grow = row0 + wr + m * 16 + orow + r;
        const float val = acc[m][n][r] + bv;
        if (OUT_BF16)
          ((unsigned short*)Cv)[grow * N + gcol] = f2bf(val);
        else
          ((float*)Cv)[grow * N + gcol] = val;
      }
    }
  }
}

// ---------------------------------------------------------------------------
// MFMA attention body, one wave per (b, h, class).
// MODE 0 = hour (14 members, t = c + 24*i), writes comb cols [0,512).
// MODE 1 = day (48 members, days dc & dc+7),   writes comb cols [512,1024).
// (verified: round 6, absmax 1.95e-3)
// ---------------------------------------------------------------------------
template <int MODE>
__device__ __forceinline__ void attn_body(
    const int cls, const int h, const int b, const int lane,
    const unsigned short* __restrict__ QKV, const float* __restrict__ bias,
    unsigned short* __restrict__ comb, unsigned short* smem) {
  constexpr int NQT = MODE ? 3 : 1;   // 16-row query tiles
  constexpr int NKT = MODE ? 3 : 1;   // 16-col key tiles
  constexpr int PVK = MODE ? 2 : 1;   // PV k-steps of 32 keys
  constexpr int MEM = MODE ? 48 : 14; // members per class
  constexpr int PLD = MODE ? 72 : 40; // P_lds row stride (elems)
  constexpr int VLD = MODE ? 72 : 40; // Vt row stride
  constexpr int PE = 16 * NQT * PLD;  // P_lds elems
  constexpr int VE = 64 * VLD;        // Vt elems

  unsigned short* P_lds = smem;
  unsigned short* Vt = smem + PE;
  const long rowBase = (long)b * 336;

  // t-mapping: class member i -> timestep
  auto tmap = [&](int i) -> int {
    if (MODE) return 24 * cls + i + ((i < 24) ? 0 : 144);
    return cls + 24 * i;
  };

  // ---- zero LDS (pad keys must multiply P as exact 0) ----
  {
    const uint4 z4 = {0u, 0u, 0u, 0u};
    uint4* p4 = (uint4*)P_lds;
#pragma unroll
    for (int i = 0; i < PE / 8 / 64 + 1; ++i) {
      const int idx = lane + i * 64;
      if (idx < PE / 8) p4[idx] = z4;
    }
    uint4* v4 = (uint4*)Vt;
#pragma unroll
    for (int i = 0; i < VE / 8 / 64 + 1; ++i) {
      const int idx = lane + i * 64;
      if (idx < VE / 8) v4[idx] = z4;
    }
  }
  __syncthreads();

  // ---- stage V transposed: Vt[d][k] (bf16), keys >= MEM stay zero ----
  {
    const int kloc = lane >> 3;        // 0..7 within pass
    const int d0 = (lane & 7) * 8;     // d octet
    constexpr int NPASS = (MEM + 7) / 8;
#pragma unroll
    for (int p = 0; p < NPASS; ++p) {
      const int k = p * 8 + kloc;
      if (k < MEM) {
        const long off = (rowBase + tmap(k)) * 1536 + 1024 + h * 64 + d0;
        const u16x8 vv = *(const u16x8*)(const void*)(QKV + off);
#pragma unroll
        for (int e = 0; e < 8; ++e) Vt[(d0 + e) * VLD + k] = vv[e];
      }
    }
  }

  // ---- Q,K fragments straight from global ----
  const int fr = lane & 15;
  const int kgrp = (lane >> 4) << 3;  // k-octet within 32-wide step
  bf16x8 aq[NQT][2], bk[NKT][2];
#pragma unroll
  for (int it = 0; it < NQT; ++it) {
    const int qi = 16 * it + fr;
    const long rq = (rowBase + tmap(qi < MEM ? qi : MEM - 1)) * 1536 + h * 64 + kgrp;
#pragma unroll
    for (int ks = 0; ks < 2; ++ks)
      aq[it][ks] = *(const bf16x8*)(const void*)(QKV + rq + ks * 32);
  }
#pragma unroll
  for (int jt = 0; jt < NKT; ++jt) {
    const int kj = 16 * jt + fr;
    const long rk = (rowBase + tmap(kj < MEM ? kj : MEM - 1)) * 1536 + 512 + h * 64 + kgrp;
#pragma unroll
    for (int ks = 0; ks < 2; ++ks)
      bk[jt][ks] = *(const bf16x8*)(const void*)(QKV + rk + ks * 32);
  }

  // ---- QK^T ----
  f32x4 sacc[NQT][NKT];
  const f32x4 zero = {0.f, 0.f, 0.f, 0.f};
#pragma unroll
  for (int it = 0; it < NQT; ++it)
#pragma unroll
    for (int jt = 0; jt < NKT; ++jt) sacc[it][jt] = zero;
#pragma unroll
  for (int ks = 0; ks < 2; ++ks)
#pragma unroll
    for (int it = 0; it < NQT; ++it)
#pragma unroll
      for (int jt = 0; jt < NKT; ++jt)
        sacc[it][jt] = __builtin_amdgcn_mfma_f32_16x16x32_bf16(aq[it][ks], bk[jt][ks], sacc[it][jt], 0, 0, 0);

  // ---- bias + mask + softmax (in-register, rows in 16-lane groups) ----
  const int rgrp = (lane >> 4) << 2;  // C-layout row group base
#pragma unroll
  for (int it = 0; it < NQT; ++it) {
#pragma unroll
    for (int r = 0; r < 4; ++r) {
      const int row = 16 * it + rgrp + r;
      const int tq = tmap(row < MEM ? row : MEM - 1);
      float sv[NKT];
#pragma unroll
      for (int jt = 0; jt < NKT; ++jt) {
        const int col = 16 * jt + fr;
        const int tk = tmap(col < MEM ? col : MEM - 1);
        sv[jt] = sacc[it][jt][r] * 0.125f + bias[(long)tq * 336 + tk];
        if (MODE == 0 && col >= MEM) sv[jt] = -1e30f;
      }
      float m = sv[0];
#pragma unroll
      for (int jt = 1; jt < NKT; ++jt) m = fmaxf(m, sv[jt]);
#pragma unroll
      for (int d = 1; d < 16; d <<= 1) m = fmaxf(m, __shfl_xor(m, d, 64));
      float e[NKT], sum = 0.f;
#pragma unroll
      for (int jt = 0; jt < NKT; ++jt) { e[jt] = __expf(sv[jt] - m); sum += e[jt]; }
#pragma unroll
      for (int d = 1; d < 16; d <<= 1) sum += __shfl_xor(sum, d, 64);
      const float inv = 1.f / sum;
#pragma unroll
      for (int jt = 0; jt < NKT; ++jt)
        P_lds[row * PLD + 16 * jt + fr] = f2bf(e[jt] * inv);
    }
  }
  __syncthreads();

  // ---- PV: O[MEM x 64] = P @ V ----
  f32x4 oacc[NQT][4];
#pragma unroll
  for (int it = 0; it < NQT; ++it)
#pragma unroll
    for (int jt = 0; jt < 4; ++jt) oacc[it][jt] = zero;
#pragma unroll
  for (int ks = 0; ks < PVK; ++ks) {
    bf16x8 pa[NQT], vb[4];
#pragma unroll
    for (int it = 0; it < NQT; ++it)
      pa[it] = *(const bf16x8*)(const void*)(P_lds + (16 * it + fr) * PLD + ks * 32 + kgrp);
#pragma unroll
    for (int jt = 0; jt < 4; ++jt)
      vb[jt] = *(const bf16x8*)(const void*)(Vt + (16 * jt + fr) * VLD + ks * 32 + kgrp);
#pragma unroll
    for (int it = 0; it < NQT; ++it)
#pragma unroll
      for (int jt = 0; jt < 4; ++jt)
        oacc[it][jt] = __builtin_amdgcn_mfma_f32_16x16x32_bf16(pa[it], vb[jt], oacc[it][jt], 0, 0, 0);
  }

  // ---- store ----
  const long colBase = (MODE ? 512 : 0) + h * 64;
#pragma unroll
  for (int it = 0; it < NQT; ++it) {
#pragma unroll
    for (int r = 0; r < 4; ++r) {
      const int row = 16 * it + rgrp + r;
      if (row < MEM) {
        const long base = (rowBase + tmap(row)) * 1024 + colBase;
#pragma unroll
        for (int jt = 0; jt < 4; ++jt)
          comb[base + 16 * jt + fr] = f2bf(oacc[it][jt][r]);
      }
    }
  }
}

// Fused hour+day attention: blocks [0,6144) = hour, [6144,7936) = day.
// LDS union sized for day (8064 ushorts = 16128 B).
__global__ __launch_bounds__(64) void attn_all(
    const unsigned short* __restrict__ QKV, const float* __restrict__ rb,
    unsigned short* __restrict__ comb) {
  __shared__ __align__(16) unsigned short smem[8064];
  const int lane = threadIdx.x & 63;
  const int bi = blockIdx.x;
  if (bi < 6144) {
    const int c = bi % 24;
    const int h = (bi / 24) & 7;
    const int b = bi / (24 * 8);
    attn_body<0>(c, h, b, lane, QKV, rb, comb, smem);
  } else {
    const int di = bi - 6144;
    const int dc = di % 7;
    const int h = (di / 7) & 7;
    const int b = di / 56;
    attn_body<1>(dc, h, b, lane, QKV, rb + 336 * 336, comb, smem);
  }
}

// ---------------------------------------------------------------------------
// Fused casts (grid-stride over three jobs)
// ---------------------------------------------------------------------------
__global__ __launch_bounds__(256) void cast_all(
    const float* __restrict__ x, const float* __restrict__ Wq,
    const float* __restrict__ Wk, const float* __restrict__ Wv,
    const float* __restrict__ Wo, unsigned short* __restrict__ xb,
    unsigned short* __restrict__ WqkvT, unsigned short* __restrict__ WoT) {
  const int g0 = blockIdx.x * 256 + threadIdx.x;
  const int gsz = gridDim.x * 256;
  // x [10752*512] f32 -> bf16, vectorized 4-wide
  for (int i = g0; i < 1376256; i += gsz) {
    const float4 v = ((const float4*)x)[i];
    ushort4 o;
    o.x = f2bf(v.x); o.y = f2bf(v.y); o.z = f2bf(v.z); o.w = f2bf(v.w);
    ((ushort4*)xb)[i] = o;
  }
  // WqkvT [1536][512]: row n<512 -> Wq col n; 512..1023 -> Wk; else Wv.
  for (int idx = g0; idx < 1536 * 512; idx += gsz) {
    const int n = idx >> 9, k = idx & 511;
    const float* W = (n < 512) ? Wq : ((n < 1024) ? Wk : Wv);
    WqkvT[idx] = f2bf(W[k * 512 + (n & 511)]);
  }
  // WoT [512][1024] = transpose of Wo [1024][512]
  for (int idx = g0; idx < 512 * 1024; idx += gsz) {
    const int n = idx >> 10, k = idx & 1023;
    WoT[idx] = f2bf(Wo[k * 512 + n]);
  }
}

// ---------------------------------------------------------------------------
extern "C" void kernel_launch(void* const* d_in, const int* in_sizes, int n_in,
                              void* d_out, int out_size, void* d_ws, size_t ws_size,
                              hipStream_t stream) {
  (void)in_sizes; (void)n_in; (void)out_size; (void)ws_size;
  const float* x  = (const float*)d_in[0];
  const float* Wq = (const float*)d_in[1];
  const float* Wk = (const float*)d_in[2];
  const float* Wv = (const float*)d_in[3];
  const float* Wo = (const float*)d_in[4];
  const float* bo = (const float*)d_in[5];
  const float* rb = (const float*)d_in[6];

  char* ws = (char*)d_ws;
  unsigned short* xbf   = (unsigned short*)(ws + 0);         // 10752*512*2  = 11,010,048
  unsigned short* WqkvT = (unsigned short*)(ws + 11010048);  // 1536*512*2   =  1,572,864
  unsigned short* WoT   = (unsigned short*)(ws + 12582912);  // 512*1024*2   =  1,048,576
  unsigned short* QKVb  = (unsigned short*)(ws + 13631488);  // 10752*1536*2 = 33,030,144
  unsigned short* comb  = (unsigned short*)(ws + 46661632);  // 10752*1024*2 = 22,020,096
  // total 68,681,728 bytes

  cast_all<<<2048, 256, 0, stream>>>(x, Wq, Wk, Wv, Wo, xbf, WqkvT, WoT);

  // QKV = x @ [Wq|Wk|Wv]  -> bf16 [10752][1536]
  gemm_bt<true><<<84 * 12, 256, 0, stream>>>(xbf, WqkvT, QKVb, nullptr, 10752, 1536, 512);

  // hour (6144 blocks) + day (1792 blocks) fused
  attn_all<<<6144 + 1792, 64, 0, stream>>>(QKVb, rb, comb);

  // out = comb @ Wo + bo -> f32 [10752][512]
  gemm_bt<false><<<84 * 4, 256, 0, stream>>>(comb, WoT, d_out, bo, 10752, 512, 1024);
}

// Round 8
// 98.760 us; speedup vs baseline: 1.8340x; 1.0435x over previous
//
#include <hip/hip_runtime.h>

// Sizes: B=32, T=336, D=512, H=8, HD=64; M = B*T = 10752.
// hour classes: 24 classes x 14 members; day classes: 7 classes x 48 members
// (days dc and dc+7).

typedef __attribute__((ext_vector_type(8))) __bf16 bf16x8;
typedef __attribute__((ext_vector_type(8))) unsigned short u16x8;
typedef __attribute__((ext_vector_type(4))) float f32x4;

__device__ __forceinline__ unsigned short f2bf(float f) {
  union { float f; unsigned u; } v; v.f = f;
  unsigned r = v.u + 0x7fffu + ((v.u >> 16) & 1u);
  return (unsigned short)(r >> 16);
}

__device__ __forceinline__ void load_lds16(const void* g, void* l) {
  __builtin_amdgcn_global_load_lds(
      (const __attribute__((address_space(1))) void*)g,
      (__attribute__((address_space(3))) void*)l, 16, 0, 0);
}

// ---------------------------------------------------------------------------
// C = A [M][K] * Bt^T, Bt stored [N][K] (both bf16 row-major, k-contiguous).
// 128x128 tile, BK=64 (2 sub-steps of 32), 4 waves (2x2 of 64x64),
// mfma_f32_16x16x32_bf16. XCD-aware block swizzle (requires gridDim%8==0).
// (math verified rounds 3/6/7, absmax 1.95e-3; BK=64+swizzle are index-only)
// ---------------------------------------------------------------------------
template <bool OUT_BF16>
__global__ __launch_bounds__(256) void gemm_bt(
    const unsigned short* __restrict__ A, const unsigned short* __restrict__ Bt,
    void* __restrict__ Cv, const float* __restrict__ bias, int M, int N, int K) {
  __shared__ __align__(16) unsigned short As[128 * 64];
  __shared__ __align__(16) unsigned short Bs[128 * 64];
  const int tid = threadIdx.x;
  const int lane = tid & 63;
  const int wid = tid >> 6;
  const int ntile = N >> 7;

  // bijective XCD swizzle: consecutive logical blocks (sharing an A-panel)
  // land on the same XCD's L2. gridDim.x % 8 == 0 for both launches.
  const int cpx = gridDim.x >> 3;
  const int bid = (blockIdx.x & 7) * cpx + (blockIdx.x >> 3);

  const int bx = bid % ntile;
  const int by = bid / ntile;
  const long row0 = (long)by << 7;
  const long col0 = (long)bx << 7;
  const int wr = (wid >> 1) << 6;
  const int wc = (wid & 1) << 6;

  // staging: 128 rows x 64 cols bf16 per matrix = 1024 lane-loads of 16B
  // -> 4 global_load_lds per matrix per K-tile.
  const unsigned short* ag[4];
  const unsigned short* bg[4];
  int lofs[4];
#pragma unroll
  for (int it = 0; it < 4; ++it) {
    const int s = tid + (it << 8);   // 0..1023
    const int r = s >> 3;            // row 0..127
    const int ko = (s & 7) << 3;     // k-octet 0..56
    ag[it] = A + (row0 + r) * (long)K + ko;
    bg[it] = Bt + (col0 + r) * (long)K + ko;
    lofs[it] = s << 4;               // byte offset in LDS (linear, wave-uniform+lane*16)
  }

  f32x4 acc[4][4];
  const f32x4 zero = {0.f, 0.f, 0.f, 0.f};
#pragma unroll
  for (int m = 0; m < 4; ++m)
#pragma unroll
    for (int n = 0; n < 4; ++n) acc[m][n] = zero;

  const int fr = lane & 15;
  const int krow = (lane >> 4) << 3;

  for (int kk = 0; kk < K; kk += 64) {
#pragma unroll
    for (int it = 0; it < 4; ++it) {
      load_lds16(ag[it] + kk, (char*)As + lofs[it]);
      load_lds16(bg[it] + kk, (char*)Bs + lofs[it]);
    }
    __syncthreads();
#pragma unroll
    for (int ks = 0; ks < 2; ++ks) {
      bf16x8 a[4], b[4];
#pragma unroll
      for (int m = 0; m < 4; ++m)
        a[m] = *(const bf16x8*)(const void*)(As + (wr + m * 16 + fr) * 64 + ks * 32 + krow);
#pragma unroll
      for (int n = 0; n < 4; ++n)
        b[n] = *(const bf16x8*)(const void*)(Bs + (wc + n * 16 + fr) * 64 + ks * 32 + krow);
#pragma unroll
      for (int m = 0; m < 4; ++m)
#pragma unroll
        for (int n = 0; n < 4; ++n)
          acc[m][n] = __builtin_amdgcn_mfma_f32_16x16x32_bf16(a[m], b[n], acc[m][n], 0, 0, 0);
    }
    __syncthreads();
  }

  // C/D layout: col = lane&15, row = (lane>>4)*4 + reg  [measured m89/m91]
  const int orow = (lane >> 4) << 2;
  const int ocol = lane & 15;
#pragma unroll
  for (int m = 0; m < 4; ++m) {
#pragma unroll
    for (int n = 0; n < 4; ++n) {
      const long gcol = col0 + wc + n * 16 + ocol;
      float bv = 0.f;
      if (!OUT_BF16 && bias) bv = bias[gcol];
#pragma unroll
      for (int r = 0; r < 4; ++r) {
        const long grow = row0 + wr + m * 16 + orow + r;
        const float val = acc[m][n][r] + bv;
        if (OUT_BF16)
          ((unsigned short*)Cv)[grow * N + gcol] = f2bf(val);
        else
          ((float*)Cv)[grow * N + gcol] = val;
      }
    }
  }
}

// ---------------------------------------------------------------------------
// MFMA attention body, one wave per (b, h, class).
// MODE 0 = hour (14 members, t = c + 24*i), writes comb cols [0,512).
// MODE 1 = day (48 members, days dc & dc+7),   writes comb cols [512,1024).
// (verified: rounds 6/7, absmax 1.95e-3)
// ---------------------------------------------------------------------------
template <int MODE>
__device__ __forceinline__ void attn_body(
    const int cls, const int h, const int b, const int lane,
    const unsigned short* __restrict__ QKV, const float* __restrict__ bias,
    unsigned short* __restrict__ comb, unsigned short* smem) {
  constexpr int NQT = MODE ? 3 : 1;   // 16-row query tiles
  constexpr int NKT = MODE ? 3 : 1;   // 16-col key tiles
  constexpr int PVK = MODE ? 2 : 1;   // PV k-steps of 32 keys
  constexpr int MEM = MODE ? 48 : 14; // members per class
  constexpr int PLD = MODE ? 72 : 40; // P_lds row stride (elems)
  constexpr int VLD = MODE ? 72 : 40; // Vt row stride
  constexpr int PE = 16 * NQT * PLD;  // P_lds elems
  constexpr int VE = 64 * VLD;        // Vt elems

  unsigned short* P_lds = smem;
  unsigned short* Vt = smem + PE;
  const long rowBase = (long)b * 336;

  // t-mapping: class member i -> timestep
  auto tmap = [&](int i) -> int {
    if (MODE) return 24 * cls + i + ((i < 24) ? 0 : 144);
    return cls + 24 * i;
  };

  // ---- zero LDS (pad keys must multiply P as exact 0) ----
  {
    const uint4 z4 = {0u, 0u, 0u, 0u};
    uint4* p4 = (uint4*)P_lds;
#pragma unroll
    for (int i = 0; i < PE / 8 / 64 + 1; ++i) {
      const int idx = lane + i * 64;
      if (idx < PE / 8) p4[idx] = z4;
    }
    uint4* v4 = (uint4*)Vt;
#pragma unroll
    for (int i = 0; i < VE / 8 / 64 + 1; ++i) {
      const int idx = lane + i * 64;
      if (idx < VE / 8) v4[idx] = z4;
    }
  }
  __syncthreads();

  // ---- stage V transposed: Vt[d][k] (bf16), keys >= MEM stay zero ----
  {
    const int kloc = lane >> 3;        // 0..7 within pass
    const int d0 = (lane & 7) * 8;     // d octet
    constexpr int NPASS = (MEM + 7) / 8;
#pragma unroll
    for (int p = 0; p < NPASS; ++p) {
      const int k = p * 8 + kloc;
      if (k < MEM) {
        const long off = (rowBase + tmap(k)) * 1536 + 1024 + h * 64 + d0;
        const u16x8 vv = *(const u16x8*)(const void*)(QKV + off);
#pragma unroll
        for (int e = 0; e < 8; ++e) Vt[(d0 + e) * VLD + k] = vv[e];
      }
    }
  }

  // ---- Q,K fragments straight from global ----
  const int fr = lane & 15;
  const int kgrp = (lane >> 4) << 3;  // k-octet within 32-wide step
  bf16x8 aq[NQT][2], bk[NKT][2];
#pragma unroll
  for (int it = 0; it < NQT; ++it) {
    const int qi = 16 * it + fr;
    const long rq = (rowBase + tmap(qi < MEM ? qi : MEM - 1)) * 1536 + h * 64 + kgrp;
#pragma unroll
    for (int ks = 0; ks < 2; ++ks)
      aq[it][ks] = *(const bf16x8*)(const void*)(QKV + rq + ks * 32);
  }
#pragma unroll
  for (int jt = 0; jt < NKT; ++jt) {
    const int kj = 16 * jt + fr;
    const long rk = (rowBase + tmap(kj < MEM ? kj : MEM - 1)) * 1536 + 512 + h * 64 + kgrp;
#pragma unroll
    for (int ks = 0; ks < 2; ++ks)
      bk[jt][ks] = *(const bf16x8*)(const void*)(QKV + rk + ks * 32);
  }

  // ---- QK^T ----
  f32x4 sacc[NQT][NKT];
  const f32x4 zero = {0.f, 0.f, 0.f, 0.f};
#pragma unroll
  for (int it = 0; it < NQT; ++it)
#pragma unroll
    for (int jt = 0; jt < NKT; ++jt) sacc[it][jt] = zero;
#pragma unroll
  for (int ks = 0; ks < 2; ++ks)
#pragma unroll
    for (int it = 0; it < NQT; ++it)
#pragma unroll
      for (int jt = 0; jt < NKT; ++jt)
        sacc[it][jt] = __builtin_amdgcn_mfma_f32_16x16x32_bf16(aq[it][ks], bk[jt][ks], sacc[it][jt], 0, 0, 0);

  // ---- bias + mask + softmax (in-register, rows in 16-lane groups) ----
  const int rgrp = (lane >> 4) << 2;  // C-layout row group base
#pragma unroll
  for (int it = 0; it < NQT; ++it) {
#pragma unroll
    for (int r = 0; r < 4; ++r) {
      const int row = 16 * it + rgrp + r;
      const int tq = tmap(row < MEM ? row : MEM - 1);
      float sv[NKT];
#pragma unroll
      for (int jt = 0; jt < NKT; ++jt) {
        const int col = 16 * jt + fr;
        const int tk = tmap(col < MEM ? col : MEM - 1);
        sv[jt] = sacc[it][jt][r] * 0.125f + bias[(long)tq * 336 + tk];
        if (MODE == 0 && col >= MEM) sv[jt] = -1e30f;
      }
      float m = sv[0];
#pragma unroll
      for (int jt = 1; jt < NKT; ++jt) m = fmaxf(m, sv[jt]);
#pragma unroll
      for (int d = 1; d < 16; d <<= 1) m = fmaxf(m, __shfl_xor(m, d, 64));
      float e[NKT], sum = 0.f;
#pragma unroll
      for (int jt = 0; jt < NKT; ++jt) { e[jt] = __expf(sv[jt] - m); sum += e[jt]; }
#pragma unroll
      for (int d = 1; d < 16; d <<= 1) sum += __shfl_xor(sum, d, 64);
      const float inv = 1.f / sum;
#pragma unroll
      for (int jt = 0; jt < NKT; ++jt)
        P_lds[row * PLD + 16 * jt + fr] = f2bf(e[jt] * inv);
    }
  }
  __syncthreads();

  // ---- PV: O[MEM x 64] = P @ V ----
  f32x4 oacc[NQT][4];
#pragma unroll
  for (int it = 0; it < NQT; ++it)
#pragma unroll
    for (int jt = 0; jt < 4; ++jt) oacc[it][jt] = zero;
#pragma unroll
  for (int ks = 0; ks < PVK; ++ks) {
    bf16x8 pa[NQT], vb[4];
#pragma unroll
    for (int it = 0; it < NQT; ++it)
      pa[it] = *(const bf16x8*)(const void*)(P_lds + (16 * it + fr) * PLD + ks * 32 + kgrp);
#pragma unroll
    for (int jt = 0; jt < 4; ++jt)
      vb[jt] = *(const bf16x8*)(const void*)(Vt + (16 * jt + fr) * VLD + ks * 32 + kgrp);
#pragma unroll
    for (int it = 0; it < NQT; ++it)
#pragma unroll
      for (int jt = 0; jt < 4; ++jt)
        oacc[it][jt] = __builtin_amdgcn_mfma_f32_16x16x32_bf16(pa[it], vb[jt], oacc[it][jt], 0, 0, 0);
  }

  // ---- store ----
  const long colBase = (MODE ? 512 : 0) + h * 64;
#pragma unroll
  for (int it = 0; it < NQT; ++it) {
#pragma unroll
    for (int r = 0; r < 4; ++r) {
      const int row = 16 * it + rgrp + r;
      if (row < MEM) {
        const long base = (rowBase + tmap(row)) * 1024 + colBase;
#pragma unroll
        for (int jt = 0; jt < 4; ++jt)
          comb[base + 16 * jt + fr] = f2bf(oacc[it][jt][r]);
      }
    }
  }
}

// Fused hour+day attention: blocks [0,6144) = hour, [6144,7936) = day.
// LDS union sized for day (8064 ushorts = 16128 B).
__global__ __launch_bounds__(64) void attn_all(
    const unsigned short* __restrict__ QKV, const float* __restrict__ rb,
    unsigned short* __restrict__ comb) {
  __shared__ __align__(16) unsigned short smem[8064];
  const int lane = threadIdx.x & 63;
  const int bi = blockIdx.x;
  if (bi < 6144) {
    const int c = bi % 24;
    const int h = (bi / 24) & 7;
    const int b = bi / (24 * 8);
    attn_body<0>(c, h, b, lane, QKV, rb, comb, smem);
  } else {
    const int di = bi - 6144;
    const int dc = di % 7;
    const int h = (di / 7) & 7;
    const int b = di / 56;
    attn_body<1>(dc, h, b, lane, QKV, rb + 336 * 336, comb, smem);
  }
}

// ---------------------------------------------------------------------------
// Fused casts (grid-stride over three jobs)
// ---------------------------------------------------------------------------
__global__ __launch_bounds__(256) void cast_all(
    const float* __restrict__ x, const float* __restrict__ Wq,
    const float* __restrict__ Wk, const float* __restrict__ Wv,
    const float* __restrict__ Wo, unsigned short* __restrict__ xb,
    unsigned short* __restrict__ WqkvT, unsigned short* __restrict__ WoT) {
  const int g0 = blockIdx.x * 256 + threadIdx.x;
  const int gsz = gridDim.x * 256;
  // x [10752*512] f32 -> bf16, vectorized 4-wide
  for (int i = g0; i < 1376256; i += gsz) {
    const float4 v = ((const float4*)x)[i];
    ushort4 o;
    o.x = f2bf(v.x); o.y = f2bf(v.y); o.z = f2bf(v.z); o.w = f2bf(v.w);
    ((ushort4*)xb)[i] = o;
  }
  // WqkvT [1536][512]: row n<512 -> Wq col n; 512..1023 -> Wk; else Wv.
  for (int idx = g0; idx < 1536 * 512; idx += gsz) {
    const int n = idx >> 9, k = idx & 511;
    const float* W = (n < 512) ? Wq : ((n < 1024) ? Wk : Wv);
    WqkvT[idx] = f2bf(W[k * 512 + (n & 511)]);
  }
  // WoT [512][1024] = transpose of Wo [1024][512]
  for (int idx = g0; idx < 512 * 1024; idx += gsz) {
    const int n = idx >> 10, k = idx & 1023;
    WoT[idx] = f2bf(Wo[k * 512 + n]);
  }
}

// ---------------------------------------------------------------------------
extern "C" void kernel_launch(void* const* d_in, const int* in_sizes, int n_in,
                              void* d_out, int out_size, void* d_ws, size_t ws_size,
                              hipStream_t stream) {
  (void)in_sizes; (void)n_in; (void)out_size; (void)ws_size;
  const float* x  = (const float*)d_in[0];
  const float* Wq = (const float*)d_in[1];
  const float* Wk = (const float*)d_in[2];
  const float* Wv = (const float*)d_in[3];
  const float* Wo = (const float*)d_in[4];
  const float* bo = (const float*)d_in[5];
  const float* rb = (const float*)d_in[6];

  char* ws = (char*)d_ws;
  unsigned short* xbf   = (unsigned short*)(ws + 0);         // 10752*512*2  = 11,010,048
  unsigned short* WqkvT = (unsigned short*)(ws + 11010048);  // 1536*512*2   =  1,572,864
  unsigned short* WoT   = (unsigned short*)(ws + 12582912);  // 512*1024*2   =  1,048,576
  unsigned short* QKVb  = (unsigned short*)(ws + 13631488);  // 10752*1536*2 = 33,030,144
  unsigned short* comb  = (unsigned short*)(ws + 46661632);  // 10752*1024*2 = 22,020,096
  // total 68,681,728 bytes

  cast_all<<<2048, 256, 0, stream>>>(x, Wq, Wk, Wv, Wo, xbf, WqkvT, WoT);

  // QKV = x @ [Wq|Wk|Wv]  -> bf16 [10752][1536]   (1008 blocks, %8==0)
  gemm_bt<true><<<84 * 12, 256, 0, stream>>>(xbf, WqkvT, QKVb, nullptr, 10752, 1536, 512);

  // hour (6144 blocks) + day (1792 blocks) fused
  attn_all<<<6144 + 1792, 64, 0, stream>>>(QKVb, rb, comb);

  // out = comb @ Wo + bo -> f32 [10752][512]      (336 blocks, %8==0)
  gemm_bt<false><<<84 * 4, 256, 0, stream>>>(comb, WoT, d_out, bo, 10752, 512, 1024);
}

// Round 9
// 85.277 us; speedup vs baseline: 2.1239x; 1.1581x over previous
//
#include <hip/hip_runtime.h>

// Sizes: B=32, T=336, D=512, H=8, HD=64; M = B*T = 10752.
// hour classes: 24 classes x 14 members; day classes: 7 classes x 48 members
// (days dc and dc+7).

typedef __attribute__((ext_vector_type(8))) __bf16 bf16x8;
typedef __attribute__((ext_vector_type(8))) unsigned short u16x8;
typedef __attribute__((ext_vector_type(4))) float f32x4;

__device__ __forceinline__ unsigned short f2bf(float f) {
  union { float f; unsigned u; } v; v.f = f;
  unsigned r = v.u + 0x7fffu + ((v.u >> 16) & 1u);
  return (unsigned short)(r >> 16);
}

__device__ __forceinline__ void load_lds16(const void* g, void* l) {
  __builtin_amdgcn_global_load_lds(
      (const __attribute__((address_space(1))) void*)g,
      (__attribute__((address_space(3))) void*)l, 16, 0, 0);
}

// ---------------------------------------------------------------------------
// C = A [M][K] * Bt^T, Bt stored [N][K] (both bf16 row-major, k-contiguous).
// BM x 128 tile (BM = 128 or 64), BK=64, 4 waves (2x2), mfma_f32_16x16x32_bf16.
// LDS rows are 128B -> chunk-XOR swizzle (T2) to kill the 16-way bank
// conflict: 16B chunk c of row r lives at LDS slot c^(r&7). Applied on BOTH
// sides (rule #21): global SOURCE pre-permuted (gload_lds dest stays linear),
// read index XORed identically -> MFMA operands bit-identical to linear.
// XCD-aware bijective block swizzle (gridDim%8==0).
// ---------------------------------------------------------------------------
template <bool OUT_BF16, int BM>
__global__ __launch_bounds__(256) void gemm_bt(
    const unsigned short* __restrict__ A, const unsigned short* __restrict__ Bt,
    void* __restrict__ Cv, const float* __restrict__ bias, int M, int N, int K) {
  constexpr int MR = BM / 32;        // m-fragments per wave
  constexpr int AIT = BM / 32;       // A staging gload_lds per thread
  __shared__ __align__(16) unsigned short As[BM * 64];
  __shared__ __align__(16) unsigned short Bs[128 * 64];
  const int tid = threadIdx.x;
  const int lane = tid & 63;
  const int wid = tid >> 6;
  const int ntile = N >> 7;

  // bijective XCD swizzle: consecutive logical blocks (sharing an A-panel)
  // land on the same XCD's L2.
  const int cpx = gridDim.x >> 3;
  const int bid = (blockIdx.x & 7) * cpx + (blockIdx.x >> 3);

  const int bx = bid % ntile;
  const int by = bid / ntile;
  const long row0 = (long)by * BM;
  const long col0 = (long)bx << 7;
  const int wr = (wid >> 1) * (BM >> 1);
  const int wc = (wid & 1) << 6;

  // staging: slot s covers row r = s>>3, 16B chunk c = s&7 of the LDS tile.
  // Source chunk is c ^ (r&7)  (inverse of the read-side XOR; involution).
  const unsigned short* ag[AIT];
  const unsigned short* bg[4];
  int alofs[AIT], blofs[4];
#pragma unroll
  for (int it = 0; it < AIT; ++it) {
    const int s = tid + (it << 8);
    const int r = s >> 3;
    const int c = s & 7;
    ag[it] = A + (row0 + r) * (long)K + (((c ^ (r & 7)) << 3));
    alofs[it] = s << 4;
  }
#pragma unroll
  for (int it = 0; it < 4; ++it) {
    const int s = tid + (it << 8);
    const int r = s >> 3;
    const int c = s & 7;
    bg[it] = Bt + (col0 + r) * (long)K + (((c ^ (r & 7)) << 3));
    blofs[it] = s << 4;
  }

  f32x4 acc[MR][4];
  const f32x4 zero = {0.f, 0.f, 0.f, 0.f};
#pragma unroll
  for (int m = 0; m < MR; ++m)
#pragma unroll
    for (int n = 0; n < 4; ++n) acc[m][n] = zero;

  const int fr = lane & 15;
  const int grp = lane >> 4;         // k-octet group 0..3
  const int sw = fr & 7;             // read-side chunk XOR

  for (int kk = 0; kk < K; kk += 64) {
#pragma unroll
    for (int it = 0; it < AIT; ++it)
      load_lds16(ag[it] + kk, (char*)As + alofs[it]);
#pragma unroll
    for (int it = 0; it < 4; ++it)
      load_lds16(bg[it] + kk, (char*)Bs + blofs[it]);
    __syncthreads();
#pragma unroll
    for (int ks = 0; ks < 2; ++ks) {
      const int kc = ks * 4 + grp;   // logical 16B chunk within the row
      bf16x8 a[MR], b[4];
#pragma unroll
      for (int m = 0; m < MR; ++m) {
        const int row = wr + m * 16 + fr;
        a[m] = *(const bf16x8*)(const void*)(As + row * 64 + ((kc ^ sw) << 3));
      }
#pragma unroll
      for (int n = 0; n < 4; ++n) {
        const int row = wc + n * 16 + fr;
        b[n] = *(const bf16x8*)(const void*)(Bs + row * 64 + ((kc ^ sw) << 3));
      }
#pragma unroll
      for (int m = 0; m < MR; ++m)
#pragma unroll
        for (int n = 0; n < 4; ++n)
          acc[m][n] = __builtin_amdgcn_mfma_f32_16x16x32_bf16(a[m], b[n], acc[m][n], 0, 0, 0);
    }
    __syncthreads();
  }

  // C/D layout: col = lane&15, row = (lane>>4)*4 + reg  [measured m89/m91]
  const int orow = (lane >> 4) << 2;
  const int ocol = lane & 15;
#pragma unroll
  for (int m = 0; m < MR; ++m) {
#pragma unroll
    for (int n = 0; n < 4; ++n) {
      const long gcol = col0 + wc + n * 16 + ocol;
      float bv = 0.f;
      if (!OUT_BF16 && bias) bv = bias[gcol];
#pragma unroll
      for (int r = 0; r < 4; ++r) {
        const long grow = row0 + wr + m * 16 + orow + r;
        const float val = acc[m][n][r] + bv;
        if (OUT_BF16)
          ((unsigned short*)Cv)[grow * N + gcol] = f2bf(val);
        else
          ((float*)Cv)[grow * N + gcol] = val;
      }
    }
  }
}

// ---------------------------------------------------------------------------
// MFMA attention body, one wave per (b, h, class).
// MODE 0 = hour (14 members, t = c + 24*i), writes comb cols [0,512).
// MODE 1 = day (48 members, days dc & dc+7),   writes comb cols [512,1024).
// (verified: rounds 6/7/8, absmax 1.95e-3)
// ---------------------------------------------------------------------------
template <int MODE>
__device__ __forceinline__ void attn_body(
    const int cls, const int h, const int b, const int lane,
    const unsigned short* __restrict__ QKV, const float* __restrict__ bias,
    unsigned short* __restrict__ comb, unsigned short* smem) {
  constexpr int NQT = MODE ? 3 : 1;   // 16-row query tiles
  constexpr int NKT = MODE ? 3 : 1;   // 16-col key tiles
  constexpr int PVK = MODE ? 2 : 1;   // PV k-steps of 32 keys
  constexpr int MEM = MODE ? 48 : 14; // members per class
  constexpr int PLD = MODE ? 72 : 40; // P_lds row stride (elems)
  constexpr int VLD = MODE ? 72 : 40; // Vt row stride
  constexpr int PE = 16 * NQT * PLD;  // P_lds elems
  constexpr int VE = 64 * VLD;        // Vt elems

  unsigned short* P_lds = smem;
  unsigned short* Vt = smem + PE;
  const long rowBase = (long)b * 336;

  // t-mapping: class member i -> timestep
  auto tmap = [&](int i) -> int {
    if (MODE) return 24 * cls + i + ((i < 24) ? 0 : 144);
    return cls + 24 * i;
  };

  // ---- zero LDS (pad keys must multiply P as exact 0) ----
  {
    const uint4 z4 = {0u, 0u, 0u, 0u};
    uint4* p4 = (uint4*)P_lds;
#pragma unroll
    for (int i = 0; i < PE / 8 / 64 + 1; ++i) {
      const int idx = lane + i * 64;
      if (idx < PE / 8) p4[idx] = z4;
    }
    uint4* v4 = (uint4*)Vt;
#pragma unroll
    for (int i = 0; i < VE / 8 / 64 + 1; ++i) {
      const int idx = lane + i * 64;
      if (idx < VE / 8) v4[idx] = z4;
    }
  }
  __syncthreads();

  // ---- stage V transposed: Vt[d][k] (bf16), keys >= MEM stay zero ----
  {
    const int kloc = lane >> 3;        // 0..7 within pass
    const int d0 = (lane & 7) * 8;     // d octet
    constexpr int NPASS = (MEM + 7) / 8;
#pragma unroll
    for (int p = 0; p < NPASS; ++p) {
      const int k = p * 8 + kloc;
      if (k < MEM) {
        const long off = (rowBase + tmap(k)) * 1536 + 1024 + h * 64 + d0;
        const u16x8 vv = *(const u16x8*)(const void*)(QKV + off);
#pragma unroll
        for (int e = 0; e < 8; ++e) Vt[(d0 + e) * VLD + k] = vv[e];
      }
    }
  }

  // ---- Q,K fragments straight from global ----
  const int fr = lane & 15;
  const int kgrp = (lane >> 4) << 3;  // k-octet within 32-wide step
  bf16x8 aq[NQT][2], bk[NKT][2];
#pragma unroll
  for (int it = 0; it < NQT; ++it) {
    const int qi = 16 * it + fr;
    const long rq = (rowBase + tmap(qi < MEM ? qi : MEM - 1)) * 1536 + h * 64 + kgrp;
#pragma unroll
    for (int ks = 0; ks < 2; ++ks)
      aq[it][ks] = *(const bf16x8*)(const void*)(QKV + rq + ks * 32);
  }
#pragma unroll
  for (int jt = 0; jt < NKT; ++jt) {
    const int kj = 16 * jt + fr;
    const long rk = (rowBase + tmap(kj < MEM ? kj : MEM - 1)) * 1536 + 512 + h * 64 + kgrp;
#pragma unroll
    for (int ks = 0; ks < 2; ++ks)
      bk[jt][ks] = *(const bf16x8*)(const void*)(QKV + rk + ks * 32);
  }

  // ---- QK^T ----
  f32x4 sacc[NQT][NKT];
  const f32x4 zero = {0.f, 0.f, 0.f, 0.f};
#pragma unroll
  for (int it = 0; it < NQT; ++it)
#pragma unroll
    for (int jt = 0; jt < NKT; ++jt) sacc[it][jt] = zero;
#pragma unroll
  for (int ks = 0; ks < 2; ++ks)
#pragma unroll
    for (int it = 0; it < NQT; ++it)
#pragma unroll
      for (int jt = 0; jt < NKT; ++jt)
        sacc[it][jt] = __builtin_amdgcn_mfma_f32_16x16x32_bf16(aq[it][ks], bk[jt][ks], sacc[it][jt], 0, 0, 0);

  // ---- bias + mask + softmax (in-register, rows in 16-lane groups) ----
  const int rgrp = (lane >> 4) << 2;  // C-layout row group base
#pragma unroll
  for (int it = 0; it < NQT; ++it) {
#pragma unroll
    for (int r = 0; r < 4; ++r) {
      const int row = 16 * it + rgrp + r;
      const int tq = tmap(row < MEM ? row : MEM - 1);
      float sv[NKT];
#pragma unroll
      for (int jt = 0; jt < NKT; ++jt) {
        const int col = 16 * jt + fr;
        const int tk = tmap(col < MEM ? col : MEM - 1);
        sv[jt] = sacc[it][jt][r] * 0.125f + bias[(long)tq * 336 + tk];
        if (MODE == 0 && col >= MEM) sv[jt] = -1e30f;
      }
      float m = sv[0];
#pragma unroll
      for (int jt = 1; jt < NKT; ++jt) m = fmaxf(m, sv[jt]);
#pragma unroll
      for (int d = 1; d < 16; d <<= 1) m = fmaxf(m, __shfl_xor(m, d, 64));
      float e[NKT], sum = 0.f;
#pragma unroll
      for (int jt = 0; jt < NKT; ++jt) { e[jt] = __expf(sv[jt] - m); sum += e[jt]; }
#pragma unroll
      for (int d = 1; d < 16; d <<= 1) sum += __shfl_xor(sum, d, 64);
      const float inv = 1.f / sum;
#pragma unroll
      for (int jt = 0; jt < NKT; ++jt)
        P_lds[row * PLD + 16 * jt + fr] = f2bf(e[jt] * inv);
    }
  }
  __syncthreads();

  // ---- PV: O[MEM x 64] = P @ V ----
  f32x4 oacc[NQT][4];
#pragma unroll
  for (int it = 0; it < NQT; ++it)
#pragma unroll
    for (int jt = 0; jt < 4; ++jt) oacc[it][jt] = zero;
#pragma unroll
  for (int ks = 0; ks < PVK; ++ks) {
    bf16x8 pa[NQT], vb[4];
#pragma unroll
    for (int it = 0; it < NQT; ++it)
      pa[it] = *(const bf16x8*)(const void*)(P_lds + (16 * it + fr) * PLD + ks * 32 + kgrp);
#pragma unroll
    for (int jt = 0; jt < 4; ++jt)
      vb[jt] = *(const bf16x8*)(const void*)(Vt + (16 * jt + fr) * VLD + ks * 32 + kgrp);
#pragma unroll
    for (int it = 0; it < NQT; ++it)
#pragma unroll
      for (int jt = 0; jt < 4; ++jt)
        oacc[it][jt] = __builtin_amdgcn_mfma_f32_16x16x32_bf16(pa[it], vb[jt], oacc[it][jt], 0, 0, 0);
  }

  // ---- store ----
  const long colBase = (MODE ? 512 : 0) + h * 64;
#pragma unroll
  for (int it = 0; it < NQT; ++it) {
#pragma unroll
    for (int r = 0; r < 4; ++r) {
      const int row = 16 * it + rgrp + r;
      if (row < MEM) {
        const long base = (rowBase + tmap(row)) * 1024 + colBase;
#pragma unroll
        for (int jt = 0; jt < 4; ++jt)
          comb[base + 16 * jt + fr] = f2bf(oacc[it][jt][r]);
      }
    }
  }
}

// Fused hour+day attention: blocks [0,6144) = hour, [6144,7936) = day.
// LDS union sized for day (8064 ushorts = 16128 B).
__global__ __launch_bounds__(64) void attn_all(
    const unsigned short* __restrict__ QKV, const float* __restrict__ rb,
    unsigned short* __restrict__ comb) {
  __shared__ __align__(16) unsigned short smem[8064];
  const int lane = threadIdx.x & 63;
  const int bi = blockIdx.x;
  if (bi < 6144) {
    const int c = bi % 24;
    const int h = (bi / 24) & 7;
    const int b = bi / (24 * 8);
    attn_body<0>(c, h, b, lane, QKV, rb, comb, smem);
  } else {
    const int di = bi - 6144;
    const int dc = di % 7;
    const int h = (di / 7) & 7;
    const int b = di / 56;
    attn_body<1>(dc, h, b, lane, QKV, rb + 336 * 336, comb, smem);
  }
}

// ---------------------------------------------------------------------------
// Fused casts (grid-stride over three jobs)
// ---------------------------------------------------------------------------
__global__ __launch_bounds__(256) void cast_all(
    const float* __restrict__ x, const float* __restrict__ Wq,
    const float* __restrict__ Wk, const float* __restrict__ Wv,
    const float* __restrict__ Wo, unsigned short* __restrict__ xb,
    unsigned short* __restrict__ WqkvT, unsigned short* __restrict__ WoT) {
  const int g0 = blockIdx.x * 256 + threadIdx.x;
  const int gsz = gridDim.x * 256;
  // x [10752*512] f32 -> bf16, vectorized 4-wide
  for (int i = g0; i < 1376256; i += gsz) {
    const float4 v = ((const float4*)x)[i];
    ushort4 o;
    o.x = f2bf(v.x); o.y = f2bf(v.y); o.z = f2bf(v.z); o.w = f2bf(v.w);
    ((ushort4*)xb)[i] = o;
  }
  // WqkvT [1536][512]: row n<512 -> Wq col n; 512..1023 -> Wk; else Wv.
  for (int idx = g0; idx < 1536 * 512; idx += gsz) {
    const int n = idx >> 9, k = idx & 511;
    const float* W = (n < 512) ? Wq : ((n < 1024) ? Wk : Wv);
    WqkvT[idx] = f2bf(W[k * 512 + (n & 511)]);
  }
  // WoT [512][1024] = transpose of Wo [1024][512]
  for (int idx = g0; idx < 512 * 1024; idx += gsz) {
    const int n = idx >> 10, k = idx & 1023;
    WoT[idx] = f2bf(Wo[k * 512 + n]);
  }
}

// ---------------------------------------------------------------------------
extern "C" void kernel_launch(void* const* d_in, const int* in_sizes, int n_in,
                              void* d_out, int out_size, void* d_ws, size_t ws_size,
                              hipStream_t stream) {
  (void)in_sizes; (void)n_in; (void)out_size; (void)ws_size;
  const float* x  = (const float*)d_in[0];
  const float* Wq = (const float*)d_in[1];
  const float* Wk = (const float*)d_in[2];
  const float* Wv = (const float*)d_in[3];
  const float* Wo = (const float*)d_in[4];
  const float* bo = (const float*)d_in[5];
  const float* rb = (const float*)d_in[6];

  char* ws = (char*)d_ws;
  unsigned short* xbf   = (unsigned short*)(ws + 0);         // 10752*512*2  = 11,010,048
  unsigned short* WqkvT = (unsigned short*)(ws + 11010048);  // 1536*512*2   =  1,572,864
  unsigned short* WoT   = (unsigned short*)(ws + 12582912);  // 512*1024*2   =  1,048,576
  unsigned short* QKVb  = (unsigned short*)(ws + 13631488);  // 10752*1536*2 = 33,030,144
  unsigned short* comb  = (unsigned short*)(ws + 46661632);  // 10752*1024*2 = 22,020,096
  // total 68,681,728 bytes

  cast_all<<<2048, 256, 0, stream>>>(x, Wq, Wk, Wv, Wo, xbf, WqkvT, WoT);

  // QKV = x @ [Wq|Wk|Wv]  -> bf16 [10752][1536]   (1008 blocks, %8==0)
  gemm_bt<true, 128><<<84 * 12, 256, 0, stream>>>(xbf, WqkvT, QKVb, nullptr, 10752, 1536, 512);

  // hour (6144 blocks) + day (1792 blocks) fused
  attn_all<<<6144 + 1792, 64, 0, stream>>>(QKVb, rb, comb);

  // out = comb @ Wo + bo -> f32 [10752][512]      (672 blocks, %8==0, BM=64 tail fix)
  gemm_bt<false, 64><<<168 * 4, 256, 0, stream>>>(comb, WoT, d_out, bo, 10752, 512, 1024);
}

// Round 10
// 84.095 us; speedup vs baseline: 2.1538x; 1.0141x over previous
//
#include <hip/hip_runtime.h>

// Sizes: B=32, T=336, D=512, H=8, HD=64; M = B*T = 10752.
// hour classes: 24 classes x 14 members; day classes: 7 classes x 48 members
// (days dc and dc+7).

typedef __attribute__((ext_vector_type(8))) __bf16 bf16x8;
typedef __attribute__((ext_vector_type(8))) unsigned short u16x8;
typedef __attribute__((ext_vector_type(4))) float f32x4;

__device__ __forceinline__ unsigned short f2bf(float f) {
  union { float f; unsigned u; } v; v.f = f;
  unsigned r = v.u + 0x7fffu + ((v.u >> 16) & 1u);
  return (unsigned short)(r >> 16);
}

__device__ __forceinline__ void load_lds16(const void* g, void* l) {
  __builtin_amdgcn_global_load_lds(
      (const __attribute__((address_space(1))) void*)g,
      (__attribute__((address_space(3))) void*)l, 16, 0, 0);
}

// ---------------------------------------------------------------------------
// C = A [M][K] * Bt^T, Bt stored [N][K] (both bf16 row-major, k-contiguous).
// BM=64 x BN=128 tile, BK=64, min-2-phase DOUBLE-BUFFERED schedule:
//   prologue: STAGE(buf0); barrier;
//   loop t:   STAGE(buf^1, t+1); ds_read+MFMA from buf; barrier; swap.
// Stage latency of tile t+1 hides under compute of tile t; one barrier/tile.
// LDS rows are 128B -> chunk-XOR swizzle (T2, verified round 9): 16B chunk c
// of row r lives at slot c^(r&7); global SOURCE pre-permuted (gload_lds dest
// linear, rule #21), read index XORed identically -> operands bit-identical.
// 4 waves (2x2 of 32x64). LDS = 2*(8+16) KB = 48 KB -> 3 blocks/CU.
// XCD-aware bijective block swizzle (gridDim%8==0).
// ---------------------------------------------------------------------------
template <bool OUT_BF16>
__global__ __launch_bounds__(256) void gemm_bt(
    const unsigned short* __restrict__ A, const unsigned short* __restrict__ Bt,
    void* __restrict__ Cv, const float* __restrict__ bias, int M, int N, int K) {
  __shared__ __align__(16) unsigned short As[2 * 64 * 64];   // 2 x 8 KB
  __shared__ __align__(16) unsigned short Bs[2 * 128 * 64];  // 2 x 16 KB
  const int tid = threadIdx.x;
  const int lane = tid & 63;
  const int wid = tid >> 6;
  const int ntile = N >> 7;

  // bijective XCD swizzle: consecutive logical blocks (sharing an A-panel)
  // land on the same XCD's L2.
  const int cpx = gridDim.x >> 3;
  const int bid = (blockIdx.x & 7) * cpx + (blockIdx.x >> 3);

  const int bx = bid % ntile;
  const int by = bid / ntile;
  const long row0 = (long)by << 6;   // BM = 64
  const long col0 = (long)bx << 7;   // BN = 128
  const int wr = (wid >> 1) << 5;    // wave rows: 0 / 32
  const int wc = (wid & 1) << 6;     // wave cols: 0 / 64

  // staging slots: slot s = row r = s>>3, 16B chunk c = s&7.
  // Source chunk = c ^ (r&7) (involution; inverse of read-side XOR).
  const unsigned short* ag[2];
  const unsigned short* bg[4];
  int alofs[2], blofs[4];
#pragma unroll
  for (int it = 0; it < 2; ++it) {
    const int s = tid + (it << 8);   // 0..511
    const int r = s >> 3;
    const int c = s & 7;
    ag[it] = A + (row0 + r) * (long)K + ((c ^ (r & 7)) << 3);
    alofs[it] = s << 4;
  }
#pragma unroll
  for (int it = 0; it < 4; ++it) {
    const int s = tid + (it << 8);   // 0..1023
    const int r = s >> 3;
    const int c = s & 7;
    bg[it] = Bt + (col0 + r) * (long)K + ((c ^ (r & 7)) << 3);
    blofs[it] = s << 4;
  }

  f32x4 acc[2][4];
  const f32x4 zero = {0.f, 0.f, 0.f, 0.f};
#pragma unroll
  for (int m = 0; m < 2; ++m)
#pragma unroll
    for (int n = 0; n < 4; ++n) acc[m][n] = zero;

  const int fr = lane & 15;
  const int grp = lane >> 4;         // k-octet group 0..3
  const int sw = fr & 7;             // read-side chunk XOR

  const int NT = K >> 6;

  // prologue: stage tile 0 into buffer 0
#pragma unroll
  for (int it = 0; it < 2; ++it)
    load_lds16(ag[it], (char*)As + alofs[it]);
#pragma unroll
  for (int it = 0; it < 4; ++it)
    load_lds16(bg[it], (char*)Bs + blofs[it]);
  __syncthreads();

  int cur = 0;
  for (int t = 0; t < NT; ++t) {
    // issue next-tile stage into the other buffer (hides under compute)
    if (t + 1 < NT) {
      const int kk = (t + 1) << 6;
      const int nb = cur ^ 1;
#pragma unroll
      for (int it = 0; it < 2; ++it)
        load_lds16(ag[it] + kk, (char*)As + nb * 8192 + alofs[it]);
#pragma unroll
      for (int it = 0; it < 4; ++it)
        load_lds16(bg[it] + kk, (char*)Bs + nb * 16384 + blofs[it]);
    }
    // compute current tile
    const unsigned short* Ab = As + cur * 4096;
    const unsigned short* Bb = Bs + cur * 8192;
#pragma unroll
    for (int ks = 0; ks < 2; ++ks) {
      const int kc = ks * 4 + grp;   // logical 16B chunk within the row
      bf16x8 a[2], b[4];
#pragma unroll
      for (int m = 0; m < 2; ++m) {
        const int row = wr + m * 16 + fr;
        a[m] = *(const bf16x8*)(const void*)(Ab + row * 64 + ((kc ^ sw) << 3));
      }
#pragma unroll
      for (int n = 0; n < 4; ++n) {
        const int row = wc + n * 16 + fr;
        b[n] = *(const bf16x8*)(const void*)(Bb + row * 64 + ((kc ^ sw) << 3));
      }
#pragma unroll
      for (int m = 0; m < 2; ++m)
#pragma unroll
        for (int n = 0; n < 4; ++n)
          acc[m][n] = __builtin_amdgcn_mfma_f32_16x16x32_bf16(a[m], b[n], acc[m][n], 0, 0, 0);
    }
    // drains the t+1 stage (landed under compute) + protects buf reuse
    __syncthreads();
    cur ^= 1;
  }

  // C/D layout: col = lane&15, row = (lane>>4)*4 + reg  [measured m89/m91]
  const int orow = (lane >> 4) << 2;
  const int ocol = lane & 15;
#pragma unroll
  for (int m = 0; m < 2; ++m) {
#pragma unroll
    for (int n = 0; n < 4; ++n) {
      const long gcol = col0 + wc + n * 16 + ocol;
      float bv = 0.f;
      if (!OUT_BF16 && bias) bv = bias[gcol];
#pragma unroll
      for (int r = 0; r < 4; ++r) {
        const long grow = row0 + wr + m * 16 + orow + r;
        const float val = acc[m][n][r] + bv;
        if (OUT_BF16)
          ((unsigned short*)Cv)[grow * N + gcol] = f2bf(val);
        else
          ((float*)Cv)[grow * N + gcol] = val;
      }
    }
  }
}

// ---------------------------------------------------------------------------
// MFMA attention body, one wave per (b, h, class).
// MODE 0 = hour (14 members, t = c + 24*i), writes comb cols [0,512).
// MODE 1 = day (48 members, days dc & dc+7),   writes comb cols [512,1024).
// (verified: rounds 6/7/8/9, absmax 1.95e-3)
// ---------------------------------------------------------------------------
template <int MODE>
__device__ __forceinline__ void attn_body(
    const int cls, const int h, const int b, const int lane,
    const unsigned short* __restrict__ QKV, const float* __restrict__ bias,
    unsigned short* __restrict__ comb, unsigned short* smem) {
  constexpr int NQT = MODE ? 3 : 1;   // 16-row query tiles
  constexpr int NKT = MODE ? 3 : 1;   // 16-col key tiles
  constexpr int PVK = MODE ? 2 : 1;   // PV k-steps of 32 keys
  constexpr int MEM = MODE ? 48 : 14; // members per class
  constexpr int PLD = MODE ? 72 : 40; // P_lds row stride (elems)
  constexpr int VLD = MODE ? 72 : 40; // Vt row stride
  constexpr int PE = 16 * NQT * PLD;  // P_lds elems
  constexpr int VE = 64 * VLD;        // Vt elems

  unsigned short* P_lds = smem;
  unsigned short* Vt = smem + PE;
  const long rowBase = (long)b * 336;

  // t-mapping: class member i -> timestep
  auto tmap = [&](int i) -> int {
    if (MODE) return 24 * cls + i + ((i < 24) ? 0 : 144);
    return cls + 24 * i;
  };

  // ---- zero LDS (pad keys must multiply P as exact 0) ----
  {
    const uint4 z4 = {0u, 0u, 0u, 0u};
    uint4* p4 = (uint4*)P_lds;
#pragma unroll
    for (int i = 0; i < PE / 8 / 64 + 1; ++i) {
      const int idx = lane + i * 64;
      if (idx < PE / 8) p4[idx] = z4;
    }
    uint4* v4 = (uint4*)Vt;
#pragma unroll
    for (int i = 0; i < VE / 8 / 64 + 1; ++i) {
      const int idx = lane + i * 64;
      if (idx < VE / 8) v4[idx] = z4;
    }
  }
  __syncthreads();

  // ---- stage V transposed: Vt[d][k] (bf16), keys >= MEM stay zero ----
  {
    const int kloc = lane >> 3;        // 0..7 within pass
    const int d0 = (lane & 7) * 8;     // d octet
    constexpr int NPASS = (MEM + 7) / 8;
#pragma unroll
    for (int p = 0; p < NPASS; ++p) {
      const int k = p * 8 + kloc;
      if (k < MEM) {
        const long off = (rowBase + tmap(k)) * 1536 + 1024 + h * 64 + d0;
        const u16x8 vv = *(const u16x8*)(const void*)(QKV + off);
#pragma unroll
        for (int e = 0; e < 8; ++e) Vt[(d0 + e) * VLD + k] = vv[e];
      }
    }
  }

  // ---- Q,K fragments straight from global ----
  const int fr = lane & 15;
  const int kgrp = (lane >> 4) << 3;  // k-octet within 32-wide step
  bf16x8 aq[NQT][2], bk[NKT][2];
#pragma unroll
  for (int it = 0; it < NQT; ++it) {
    const int qi = 16 * it + fr;
    const long rq = (rowBase + tmap(qi < MEM ? qi : MEM - 1)) * 1536 + h * 64 + kgrp;
#pragma unroll
    for (int ks = 0; ks < 2; ++ks)
      aq[it][ks] = *(const bf16x8*)(const void*)(QKV + rq + ks * 32);
  }
#pragma unroll
  for (int jt = 0; jt < NKT; ++jt) {
    const int kj = 16 * jt + fr;
    const long rk = (rowBase + tmap(kj < MEM ? kj : MEM - 1)) * 1536 + 512 + h * 64 + kgrp;
#pragma unroll
    for (int ks = 0; ks < 2; ++ks)
      bk[jt][ks] = *(const bf16x8*)(const void*)(QKV + rk + ks * 32);
  }

  // ---- QK^T ----
  f32x4 sacc[NQT][NKT];
  const f32x4 zero = {0.f, 0.f, 0.f, 0.f};
#pragma unroll
  for (int it = 0; it < NQT; ++it)
#pragma unroll
    for (int jt = 0; jt < NKT; ++jt) sacc[it][jt] = zero;
#pragma unroll
  for (int ks = 0; ks < 2; ++ks)
#pragma unroll
    for (int it = 0; it < NQT; ++it)
#pragma unroll
      for (int jt = 0; jt < NKT; ++jt)
        sacc[it][jt] = __builtin_amdgcn_mfma_f32_16x16x32_bf16(aq[it][ks], bk[jt][ks], sacc[it][jt], 0, 0, 0);

  // ---- bias + mask + softmax (in-register, rows in 16-lane groups) ----
  const int rgrp = (lane >> 4) << 2;  // C-layout row group base
#pragma unroll
  for (int it = 0; it < NQT; ++it) {
#pragma unroll
    for (int r = 0; r < 4; ++r) {
      const int row = 16 * it + rgrp + r;
      const int tq = tmap(row < MEM ? row : MEM - 1);
      float sv[NKT];
#pragma unroll
      for (int jt = 0; jt < NKT; ++jt) {
        const int col = 16 * jt + fr;
        const int tk = tmap(col < MEM ? col : MEM - 1);
        sv[jt] = sacc[it][jt][r] * 0.125f + bias[(long)tq * 336 + tk];
        if (MODE == 0 && col >= MEM) sv[jt] = -1e30f;
      }
      float m = sv[0];
#pragma unroll
      for (int jt = 1; jt < NKT; ++jt) m = fmaxf(m, sv[jt]);
#pragma unroll
      for (int d = 1; d < 16; d <<= 1) m = fmaxf(m, __shfl_xor(m, d, 64));
      float e[NKT], sum = 0.f;
#pragma unroll
      for (int jt = 0; jt < NKT; ++jt) { e[jt] = __expf(sv[jt] - m); sum += e[jt]; }
#pragma unroll
      for (int d = 1; d < 16; d <<= 1) sum += __shfl_xor(sum, d, 64);
      const float inv = 1.f / sum;
#pragma unroll
      for (int jt = 0; jt < NKT; ++jt)
        P_lds[row * PLD + 16 * jt + fr] = f2bf(e[jt] * inv);
    }
  }
  __syncthreads();

  // ---- PV: O[MEM x 64] = P @ V ----
  f32x4 oacc[NQT][4];
#pragma unroll
  for (int it = 0; it < NQT; ++it)
#pragma unroll
    for (int jt = 0; jt < 4; ++jt) oacc[it][jt] = zero;
#pragma unroll
  for (int ks = 0; ks < PVK; ++ks) {
    bf16x8 pa[NQT], vb[4];
#pragma unroll
    for (int it = 0; it < NQT; ++it)
      pa[it] = *(const bf16x8*)(const void*)(P_lds + (16 * it + fr) * PLD + ks * 32 + kgrp);
#pragma unroll
    for (int jt = 0; jt < 4; ++jt)
      vb[jt] = *(const bf16x8*)(const void*)(Vt + (16 * jt + fr) * VLD + ks * 32 + kgrp);
#pragma unroll
    for (int it = 0; it < NQT; ++it)
#pragma unroll
      for (int jt = 0; jt < 4; ++jt)
        oacc[it][jt] = __builtin_amdgcn_mfma_f32_16x16x32_bf16(pa[it], vb[jt], oacc[it][jt], 0, 0, 0);
  }

  // ---- store ----
  const long colBase = (MODE ? 512 : 0) + h * 64;
#pragma unroll
  for (int it = 0; it < NQT; ++it) {
#pragma unroll
    for (int r = 0; r < 4; ++r) {
      const int row = 16 * it + rgrp + r;
      if (row < MEM) {
        const long base = (rowBase + tmap(row)) * 1024 + colBase;
#pragma unroll
        for (int jt = 0; jt < 4; ++jt)
          comb[base + 16 * jt + fr] = f2bf(oacc[it][jt][r]);
      }
    }
  }
}

// Fused hour+day attention: blocks [0,6144) = hour, [6144,7936) = day.
// LDS union sized for day (8064 ushorts = 16128 B).
__global__ __launch_bounds__(64) void attn_all(
    const unsigned short* __restrict__ QKV, const float* __restrict__ rb,
    unsigned short* __restrict__ comb) {
  __shared__ __align__(16) unsigned short smem[8064];
  const int lane = threadIdx.x & 63;
  const int bi = blockIdx.x;
  if (bi < 6144) {
    const int c = bi % 24;
    const int h = (bi / 24) & 7;
    const int b = bi / (24 * 8);
    attn_body<0>(c, h, b, lane, QKV, rb, comb, smem);
  } else {
    const int di = bi - 6144;
    const int dc = di % 7;
    const int h = (di / 7) & 7;
    const int b = di / 56;
    attn_body<1>(dc, h, b, lane, QKV, rb + 336 * 336, comb, smem);
  }
}

// ---------------------------------------------------------------------------
// Fused casts (grid-stride over three jobs)
// ---------------------------------------------------------------------------
__global__ __launch_bounds__(256) void cast_all(
    const float* __restrict__ x, const float* __restrict__ Wq,
    const float* __restrict__ Wk, const float* __restrict__ Wv,
    const float* __restrict__ Wo, unsigned short* __restrict__ xb,
    unsigned short* __restrict__ WqkvT, unsigned short* __restrict__ WoT) {
  const int g0 = blockIdx.x * 256 + threadIdx.x;
  const int gsz = gridDim.x * 256;
  // x [10752*512] f32 -> bf16, vectorized 4-wide
  for (int i = g0; i < 1376256; i += gsz) {
    const float4 v = ((const float4*)x)[i];
    ushort4 o;
    o.x = f2bf(v.x); o.y = f2bf(v.y); o.z = f2bf(v.z); o.w = f2bf(v.w);
    ((ushort4*)xb)[i] = o;
  }
  // WqkvT [1536][512]: row n<512 -> Wq col n; 512..1023 -> Wk; else Wv.
  for (int idx = g0; idx < 1536 * 512; idx += gsz) {
    const int n = idx >> 9, k = idx & 511;
    const float* W = (n < 512) ? Wq : ((n < 1024) ? Wk : Wv);
    WqkvT[idx] = f2bf(W[k * 512 + (n & 511)]);
  }
  // WoT [512][1024] = transpose of Wo [1024][512]
  for (int idx = g0; idx < 512 * 1024; idx += gsz) {
    const int n = idx >> 10, k = idx & 1023;
    WoT[idx] = f2bf(Wo[k * 512 + n]);
  }
}

// ---------------------------------------------------------------------------
extern "C" void kernel_launch(void* const* d_in, const int* in_sizes, int n_in,
                              void* d_out, int out_size, void* d_ws, size_t ws_size,
                              hipStream_t stream) {
  (void)in_sizes; (void)n_in; (void)out_size; (void)ws_size;
  const float* x  = (const float*)d_in[0];
  const float* Wq = (const float*)d_in[1];
  const float* Wk = (const float*)d_in[2];
  const float* Wv = (const float*)d_in[3];
  const float* Wo = (const float*)d_in[4];
  const float* bo = (const float*)d_in[5];
  const float* rb = (const float*)d_in[6];

  char* ws = (char*)d_ws;
  unsigned short* xbf   = (unsigned short*)(ws + 0);         // 10752*512*2  = 11,010,048
  unsigned short* WqkvT = (unsigned short*)(ws + 11010048);  // 1536*512*2   =  1,572,864
  unsigned short* WoT   = (unsigned short*)(ws + 12582912);  // 512*1024*2   =  1,048,576
  unsigned short* QKVb  = (unsigned short*)(ws + 13631488);  // 10752*1536*2 = 33,030,144
  unsigned short* comb  = (unsigned short*)(ws + 46661632);  // 10752*1024*2 = 22,020,096
  // total 68,681,728 bytes

  cast_all<<<2048, 256, 0, stream>>>(x, Wq, Wk, Wv, Wo, xbf, WqkvT, WoT);

  // QKV = x @ [Wq|Wk|Wv]  -> bf16 [10752][1536]   (168*12 = 2016 blocks, %8==0)
  gemm_bt<true><<<168 * 12, 256, 0, stream>>>(xbf, WqkvT, QKVb, nullptr, 10752, 1536, 512);

  // hour (6144 blocks) + day (1792 blocks) fused
  attn_all<<<6144 + 1792, 64, 0, stream>>>(QKVb, rb, comb);

  // out = comb @ Wo + bo -> f32 [10752][512]      (168*4 = 672 blocks, %8==0)
  gemm_bt<false><<<168 * 4, 256, 0, stream>>>(comb, WoT, d_out, bo, 10752, 512, 1024);
}